// Round 4
// baseline (1053.452 us; speedup 1.0000x reference)
//
#include <hip/hip_runtime.h>
#include <hip/hip_bf16.h>
#include <math.h>

// ---------------------------------------------------------------------------
// GCN GraphRegressor: 3x (linear -> gather*norm -> scatter-sum -> relu)
//                     -> segment-mean pool -> MLP head
// R4: aggregate = HALF-wave per node, 8-deep padded gather unroll (16 loads
//     in flight per wave), nontemporal float4 gathers (skip L1 allocate).
//     Pool remains atomic-free segmented reduction fused with MLP head.
// ---------------------------------------------------------------------------

typedef float f32x4 __attribute__((ext_vector_type(4)));

__global__ void count_deg_kernel(const int* __restrict__ dst, int* __restrict__ indeg, int E) {
  int e = blockIdx.x * 256 + threadIdx.x;
  if (e < E) atomicAdd(&indeg[dst[e]], 1);
}

// ---- 3-phase exclusive scan of (indeg[i]+1) into ptr[0..n] ----------------
__global__ __launch_bounds__(1024) void tile_reduce_kernel(
    const int* __restrict__ indeg, int* __restrict__ tilesum, int n) {
  __shared__ int ws[16];
  int i = blockIdx.x * 1024 + threadIdx.x;
  int v = (i < n) ? (indeg[i] + 1) : 0;
  for (int off = 32; off > 0; off >>= 1) v += __shfl_down(v, off);
  int wid = threadIdx.x >> 6, lane = threadIdx.x & 63;
  if (lane == 0) ws[wid] = v;
  __syncthreads();
  if (threadIdx.x == 0) {
    int s = 0;
    for (int w = 0; w < 16; ++w) s += ws[w];
    tilesum[blockIdx.x] = s;
  }
}

__global__ __launch_bounds__(128) void scan_tiles_kernel(
    const int* __restrict__ tilesum, int* __restrict__ tileoff,
    int* __restrict__ ptr_last, int T) {
  __shared__ int sm[128];
  int v = (threadIdx.x < T) ? tilesum[threadIdx.x] : 0;
  sm[threadIdx.x] = v;
  __syncthreads();
  for (int off = 1; off < 128; off <<= 1) {
    int t = (threadIdx.x >= off) ? sm[threadIdx.x - off] : 0;
    __syncthreads();
    sm[threadIdx.x] += t;
    __syncthreads();
  }
  if (threadIdx.x < T) tileoff[threadIdx.x] = sm[threadIdx.x] - v;
  if (threadIdx.x == 127) *ptr_last = sm[127];
}

__global__ __launch_bounds__(1024) void scan_emit_kernel(
    const int* __restrict__ indeg, const int* __restrict__ tileoff,
    int* __restrict__ ptr, int n) {
  __shared__ int wsum[16];
  int i = blockIdx.x * 1024 + threadIdx.x;
  int v = (i < n) ? (indeg[i] + 1) : 0;
  int lane = threadIdx.x & 63, wid = threadIdx.x >> 6;
  int x = v;
  for (int off = 1; off < 64; off <<= 1) {
    int y = __shfl_up(x, off);
    if (lane >= off) x += y;
  }
  if (lane == 63) wsum[wid] = x;
  __syncthreads();
  if (threadIdx.x == 0) {
    int run = 0;
    for (int w = 0; w < 16; ++w) { int t = wsum[w]; wsum[w] = run; run += t; }
  }
  __syncthreads();
  if (i < n) ptr[i] = x - v + wsum[wid] + tileoff[blockIdx.x];
}

__global__ void fill_edges_kernel(const int* __restrict__ src, const int* __restrict__ dst,
                                  const int* __restrict__ indeg, const int* __restrict__ ptr,
                                  int* __restrict__ cursor, int* __restrict__ csrc,
                                  float* __restrict__ cnorm, int E) {
  int e = blockIdx.x * 256 + threadIdx.x;
  if (e >= E) return;
  int s = src[e], d = dst[e];
  int pos = ptr[d] + atomicAdd(&cursor[d], 1);
  csrc[pos] = s;
  float dd = (float)(indeg[s] + 1) * (float)(indeg[d] + 1);
  cnorm[pos] = 1.0f / sqrtf(dd);
}

__global__ void fill_self_kernel(const int* __restrict__ indeg, const int* __restrict__ ptr,
                                 int* __restrict__ cursor, int* __restrict__ csrc,
                                 float* __restrict__ cnorm, int n) {
  int i = blockIdx.x * 256 + threadIdx.x;
  if (i >= n) return;
  int pos = ptr[i] + atomicAdd(&cursor[i], 1);
  csrc[pos] = i;
  cnorm[pos] = 1.0f / (float)(indeg[i] + 1);
}

// graph boundaries from sorted batch: gptr[g] = first node with batch >= g
__global__ void graph_bounds_kernel(const int* __restrict__ batch,
                                    int* __restrict__ gptr, int n, int G) {
  int i = blockIdx.x * 256 + threadIdx.x;
  if (i >= n) return;
  int b = batch[i];
  if (i == 0) {
    for (int g = 0; g <= b; ++g) gptr[g] = 0;
  } else {
    int bp = batch[i - 1];
    for (int g = bp + 1; g <= b; ++g) gptr[g] = i;
  }
  if (i == n - 1) {
    for (int g = b + 1; g <= G; ++g) gptr[g] = n;
  }
}

// H[n,128] = X[n,128] @ W[128,128] + bias ; thread = 4 rows x 8 cols, k by 4
__global__ __launch_bounds__(256) void gemm_bias_kernel(
    const float* __restrict__ X, const float* __restrict__ W,
    const float* __restrict__ bias, float* __restrict__ H, int n) {
  int t = threadIdx.x;
  int col0 = (t & 15) * 8;
  int rbase = blockIdx.x * 64 + (t >> 4) * 4;
  const float* xp0 = X + (size_t)min(rbase + 0, n - 1) * 128;
  const float* xp1 = X + (size_t)min(rbase + 1, n - 1) * 128;
  const float* xp2 = X + (size_t)min(rbase + 2, n - 1) * 128;
  const float* xp3 = X + (size_t)min(rbase + 3, n - 1) * 128;
  float acc[4][8];
#pragma unroll
  for (int r = 0; r < 4; ++r)
#pragma unroll
    for (int c = 0; c < 8; ++c) acc[r][c] = 0.f;

  for (int k = 0; k < 128; k += 4) {
    float4 xv[4];
    xv[0] = *(const float4*)(xp0 + k);
    xv[1] = *(const float4*)(xp1 + k);
    xv[2] = *(const float4*)(xp2 + k);
    xv[3] = *(const float4*)(xp3 + k);
#pragma unroll
    for (int kk = 0; kk < 4; ++kk) {
      const float* wrow = W + (size_t)(k + kk) * 128 + col0;
      float4 wa = *(const float4*)(wrow);
      float4 wb = *(const float4*)(wrow + 4);
#pragma unroll
      for (int r = 0; r < 4; ++r) {
        float xs = ((const float*)&xv[r])[kk];
        acc[r][0] = fmaf(xs, wa.x, acc[r][0]);
        acc[r][1] = fmaf(xs, wa.y, acc[r][1]);
        acc[r][2] = fmaf(xs, wa.z, acc[r][2]);
        acc[r][3] = fmaf(xs, wa.w, acc[r][3]);
        acc[r][4] = fmaf(xs, wb.x, acc[r][4]);
        acc[r][5] = fmaf(xs, wb.y, acc[r][5]);
        acc[r][6] = fmaf(xs, wb.z, acc[r][6]);
        acc[r][7] = fmaf(xs, wb.w, acc[r][7]);
      }
    }
  }
  float4 ba = *(const float4*)(bias + col0);
  float4 bb = *(const float4*)(bias + col0 + 4);
#pragma unroll
  for (int r = 0; r < 4; ++r) {
    int row = rbase + r;
    if (row < n) {
      float4 o0 = {acc[r][0] + ba.x, acc[r][1] + ba.y, acc[r][2] + ba.z, acc[r][3] + ba.w};
      float4 o1 = {acc[r][4] + bb.x, acc[r][5] + bb.y, acc[r][6] + bb.z, acc[r][7] + bb.w};
      *(float4*)(H + (size_t)row * 128 + col0) = o0;
      *(float4*)(H + (size_t)row * 128 + col0 + 4) = o1;
    }
  }
}

// Aggregate: HALF-wave (32 lanes) per node, lane = 4 channels (float4).
// Edge chunk padded to multiple of 8 with zero-norm dummies (src=0) so the
// inner loop is ALWAYS 8 independent gathers -> 16 loads in flight per wave.
__global__ __launch_bounds__(256) void aggregate_kernel(
    const float* __restrict__ H, const int* __restrict__ ptr,
    const int* __restrict__ csrc, const float* __restrict__ cnorm,
    float* __restrict__ Xout, int n) {
  int node = blockIdx.x * 8 + (threadIdx.x >> 5);
  if (node >= n) return;
  int hl = threadIdx.x & 31;
  int beg = ptr[node], end = ptr[node + 1];
  f32x4 a0 = 0.f, a1 = 0.f, a2 = 0.f, a3 = 0.f;
  f32x4 a4 = 0.f, a5 = 0.f, a6 = 0.f, a7 = 0.f;
  const f32x4* Hc = (const f32x4*)(H + hl * 4);
  for (int base = beg; base < end; base += 32) {
    int m = end - base;
    if (m > 32) m = 32;
    int idx = base + hl;
    int sl = (hl < m) ? csrc[idx] : 0;
    float nl = (hl < m) ? cnorm[idx] : 0.f;
    int rounds = (m + 7) >> 3;
    for (int r = 0; r < rounds; ++r) {
      int j = r * 8;
      int s0 = __shfl(sl, j + 0, 32), s1 = __shfl(sl, j + 1, 32);
      int s2 = __shfl(sl, j + 2, 32), s3 = __shfl(sl, j + 3, 32);
      int s4 = __shfl(sl, j + 4, 32), s5 = __shfl(sl, j + 5, 32);
      int s6 = __shfl(sl, j + 6, 32), s7 = __shfl(sl, j + 7, 32);
      float n0 = __shfl(nl, j + 0, 32), n1 = __shfl(nl, j + 1, 32);
      float n2 = __shfl(nl, j + 2, 32), n3 = __shfl(nl, j + 3, 32);
      float n4 = __shfl(nl, j + 4, 32), n5 = __shfl(nl, j + 5, 32);
      float n6 = __shfl(nl, j + 6, 32), n7 = __shfl(nl, j + 7, 32);
      f32x4 h0 = __builtin_nontemporal_load(Hc + (size_t)s0 * 32);
      f32x4 h1 = __builtin_nontemporal_load(Hc + (size_t)s1 * 32);
      f32x4 h2 = __builtin_nontemporal_load(Hc + (size_t)s2 * 32);
      f32x4 h3 = __builtin_nontemporal_load(Hc + (size_t)s3 * 32);
      f32x4 h4 = __builtin_nontemporal_load(Hc + (size_t)s4 * 32);
      f32x4 h5 = __builtin_nontemporal_load(Hc + (size_t)s5 * 32);
      f32x4 h6 = __builtin_nontemporal_load(Hc + (size_t)s6 * 32);
      f32x4 h7 = __builtin_nontemporal_load(Hc + (size_t)s7 * 32);
      a0 += h0 * n0; a1 += h1 * n1; a2 += h2 * n2; a3 += h3 * n3;
      a4 += h4 * n4; a5 += h5 * n5; a6 += h6 * n6; a7 += h7 * n7;
    }
  }
  f32x4 s = ((a0 + a1) + (a2 + a3)) + ((a4 + a5) + (a6 + a7));
  f32x4 o;
  o.x = fmaxf(s.x, 0.f);
  o.y = fmaxf(s.y, 0.f);
  o.z = fmaxf(s.z, 0.f);
  o.w = fmaxf(s.w, 0.f);
  *(f32x4*)(Xout + (size_t)node * 128 + hl * 4) = o;
}

// Pool (segment-mean over sorted batch, atomic-free) + MLP head, fused.
// One block of 128 threads per graph.
__global__ __launch_bounds__(128) void pool_head_kernel(
    const float* __restrict__ X, const int* __restrict__ gptr,
    const float* __restrict__ Wp1, const float* __restrict__ bp1,
    const float* __restrict__ Wp2, const float* __restrict__ bp2,
    float* __restrict__ out, int G) {
  int g = blockIdx.x;
  int j = threadIdx.x;
  int beg = gptr[g], end = gptr[g + 1];
  __shared__ float ps[128];
  __shared__ float hs[128];
  float s0 = 0.f, s1 = 0.f, s2 = 0.f, s3 = 0.f;
  int i = beg;
  for (; i + 3 < end; i += 4) {
    s0 += X[(size_t)i * 128 + j];
    s1 += X[(size_t)(i + 1) * 128 + j];
    s2 += X[(size_t)(i + 2) * 128 + j];
    s3 += X[(size_t)(i + 3) * 128 + j];
  }
  for (; i < end; ++i) s0 += X[(size_t)i * 128 + j];
  float inv = 1.0f / (float)max(end - beg, 1);
  ps[j] = ((s0 + s1) + (s2 + s3)) * inv;
  __syncthreads();
  float acc = bp1[j];
#pragma unroll 8
  for (int k = 0; k < 128; ++k) acc = fmaf(ps[k], Wp1[k * 128 + j], acc);
  hs[j] = fmaxf(acc, 0.f) * Wp2[j];
  __syncthreads();
  for (int off = 64; off > 0; off >>= 1) {
    if (j < off) hs[j] += hs[j + off];
    __syncthreads();
  }
  if (j == 0) out[g] = hs[0] + bp2[0];
}

extern "C" void kernel_launch(void* const* d_in, const int* in_sizes, int n_in,
                              void* d_out, int out_size, void* d_ws, size_t ws_size,
                              hipStream_t stream) {
  const float* x    = (const float*)d_in[0];
  const int*   eidx = (const int*)d_in[1];
  const int*   batch= (const int*)d_in[2];
  const float* W0 = (const float*)d_in[3];
  const float* b0 = (const float*)d_in[4];
  const float* W1 = (const float*)d_in[5];
  const float* b1 = (const float*)d_in[6];
  const float* W2 = (const float*)d_in[7];
  const float* b2 = (const float*)d_in[8];
  const float* Wp1 = (const float*)d_in[9];
  const float* bp1 = (const float*)d_in[10];
  const float* Wp2 = (const float*)d_in[11];
  const float* bp2 = (const float*)d_in[12];
  float* out = (float*)d_out;

  const int N = in_sizes[0] / 128;
  const int E = in_sizes[1] / 2;
  const int G = out_size;
  const int M = E + N;
  const int T = (N + 1023) / 1024;  // #scan tiles; N<=131072 keeps T<=128

  const int* src = eidx;
  const int* dst = eidx + E;

  char* ws = (char*)d_ws;
  size_t off = 0;
  auto alloc = [&](size_t bytes) -> void* {
    void* p = ws + off;
    off = (off + bytes + 255) & ~(size_t)255;
    return p;
  };
  int*   indeg   = (int*)  alloc((size_t)N * 4);
  int*   ptr     = (int*)  alloc((size_t)(N + 1) * 4);
  int*   cursor  = (int*)  alloc((size_t)N * 4);
  int*   csrc    = (int*)  alloc((size_t)M * 4);
  float* cnorm   = (float*)alloc((size_t)M * 4);
  float* bufH    = (float*)alloc((size_t)N * 128 * 4);
  float* bufX    = (float*)alloc((size_t)N * 128 * 4);
  int*   gptr    = (int*)  alloc((size_t)(G + 1) * 4);
  int*   tilesum = (int*)  alloc((size_t)T * 4);
  int*   tileoff = (int*)  alloc((size_t)T * 4);
  (void)ws_size;

  hipMemsetAsync(indeg,  0, (size_t)N * 4, stream);
  hipMemsetAsync(cursor, 0, (size_t)N * 4, stream);

  count_deg_kernel<<<(E + 255) / 256, 256, 0, stream>>>(dst, indeg, E);
  tile_reduce_kernel<<<T, 1024, 0, stream>>>(indeg, tilesum, N);
  scan_tiles_kernel<<<1, 128, 0, stream>>>(tilesum, tileoff, ptr + N, T);
  scan_emit_kernel<<<T, 1024, 0, stream>>>(indeg, tileoff, ptr, N);
  fill_edges_kernel<<<(E + 255) / 256, 256, 0, stream>>>(src, dst, indeg, ptr, cursor, csrc, cnorm, E);
  fill_self_kernel<<<(N + 255) / 256, 256, 0, stream>>>(indeg, ptr, cursor, csrc, cnorm, N);
  graph_bounds_kernel<<<(N + 255) / 256, 256, 0, stream>>>(batch, gptr, N, G);

  dim3 gemm_grid((N + 63) / 64);
  dim3 agg_grid((N + 7) / 8);

  gemm_bias_kernel<<<gemm_grid, 256, 0, stream>>>(x,    W0, b0, bufH, N);
  aggregate_kernel<<<agg_grid, 256, 0, stream>>>(bufH, ptr, csrc, cnorm, bufX, N);
  gemm_bias_kernel<<<gemm_grid, 256, 0, stream>>>(bufX, W1, b1, bufH, N);
  aggregate_kernel<<<agg_grid, 256, 0, stream>>>(bufH, ptr, csrc, cnorm, bufX, N);
  gemm_bias_kernel<<<gemm_grid, 256, 0, stream>>>(bufX, W2, b2, bufH, N);
  aggregate_kernel<<<agg_grid, 256, 0, stream>>>(bufH, ptr, csrc, cnorm, bufX, N);

  pool_head_kernel<<<G, 128, 0, stream>>>(bufX, gptr, Wp1, bp1, Wp2, bp2, out, G);
}

// Round 5
// 854.877 us; speedup vs baseline: 1.2323x; 1.2323x over previous
//
#include <hip/hip_runtime.h>
#include <hip/hip_bf16.h>
#include <math.h>

// ---------------------------------------------------------------------------
// GCN GraphRegressor: 3x (linear -> gather*norm -> scatter-sum -> relu)
//                     -> segment-mean pool -> MLP head
// R5: aggregate = HALF-wave per node, float4 gathers, GUARDED 8-deep unroll
//     (16 loads in flight/wave), NO nontemporal (cache residency is the
//     asset: ~50% of gather demand is served by L2/L3), no dummy loads.
//     Edge metadata packed int2 (src, norm bits): 1 load/edge, 1 store/fill.
//     GEMM widened to 8 rows/thread. Pool = atomic-free segmented + head.
// ---------------------------------------------------------------------------

typedef float f32x4 __attribute__((ext_vector_type(4)));

__global__ void count_deg_kernel(const int* __restrict__ dst, int* __restrict__ indeg, int E) {
  int e = blockIdx.x * 256 + threadIdx.x;
  if (e < E) atomicAdd(&indeg[dst[e]], 1);
}

// ---- 3-phase exclusive scan of (indeg[i]+1) into ptr[0..n] ----------------
__global__ __launch_bounds__(1024) void tile_reduce_kernel(
    const int* __restrict__ indeg, int* __restrict__ tilesum, int n) {
  __shared__ int ws[16];
  int i = blockIdx.x * 1024 + threadIdx.x;
  int v = (i < n) ? (indeg[i] + 1) : 0;
  for (int off = 32; off > 0; off >>= 1) v += __shfl_down(v, off);
  int wid = threadIdx.x >> 6, lane = threadIdx.x & 63;
  if (lane == 0) ws[wid] = v;
  __syncthreads();
  if (threadIdx.x == 0) {
    int s = 0;
    for (int w = 0; w < 16; ++w) s += ws[w];
    tilesum[blockIdx.x] = s;
  }
}

__global__ __launch_bounds__(128) void scan_tiles_kernel(
    const int* __restrict__ tilesum, int* __restrict__ tileoff,
    int* __restrict__ ptr_last, int T) {
  __shared__ int sm[128];
  int v = (threadIdx.x < T) ? tilesum[threadIdx.x] : 0;
  sm[threadIdx.x] = v;
  __syncthreads();
  for (int off = 1; off < 128; off <<= 1) {
    int t = (threadIdx.x >= off) ? sm[threadIdx.x - off] : 0;
    __syncthreads();
    sm[threadIdx.x] += t;
    __syncthreads();
  }
  if (threadIdx.x < T) tileoff[threadIdx.x] = sm[threadIdx.x] - v;
  if (threadIdx.x == 127) *ptr_last = sm[127];
}

__global__ __launch_bounds__(1024) void scan_emit_kernel(
    const int* __restrict__ indeg, const int* __restrict__ tileoff,
    int* __restrict__ ptr, int n) {
  __shared__ int wsum[16];
  int i = blockIdx.x * 1024 + threadIdx.x;
  int v = (i < n) ? (indeg[i] + 1) : 0;
  int lane = threadIdx.x & 63, wid = threadIdx.x >> 6;
  int x = v;
  for (int off = 1; off < 64; off <<= 1) {
    int y = __shfl_up(x, off);
    if (lane >= off) x += y;
  }
  if (lane == 63) wsum[wid] = x;
  __syncthreads();
  if (threadIdx.x == 0) {
    int run = 0;
    for (int w = 0; w < 16; ++w) { int t = wsum[w]; wsum[w] = run; run += t; }
  }
  __syncthreads();
  if (i < n) ptr[i] = x - v + wsum[wid] + tileoff[blockIdx.x];
}

__global__ void fill_edges_kernel(const int* __restrict__ src, const int* __restrict__ dst,
                                  const int* __restrict__ indeg, const int* __restrict__ ptr,
                                  int* __restrict__ cursor, int2* __restrict__ emeta, int E) {
  int e = blockIdx.x * 256 + threadIdx.x;
  if (e >= E) return;
  int s = src[e], d = dst[e];
  int pos = ptr[d] + atomicAdd(&cursor[d], 1);
  float dd = (float)(indeg[s] + 1) * (float)(indeg[d] + 1);
  float nm = 1.0f / sqrtf(dd);
  emeta[pos] = make_int2(s, __float_as_int(nm));
}

__global__ void fill_self_kernel(const int* __restrict__ indeg, const int* __restrict__ ptr,
                                 int* __restrict__ cursor, int2* __restrict__ emeta, int n) {
  int i = blockIdx.x * 256 + threadIdx.x;
  if (i >= n) return;
  int pos = ptr[i] + atomicAdd(&cursor[i], 1);
  float nm = 1.0f / (float)(indeg[i] + 1);
  emeta[pos] = make_int2(i, __float_as_int(nm));
}

// graph boundaries from sorted batch: gptr[g] = first node with batch >= g
__global__ void graph_bounds_kernel(const int* __restrict__ batch,
                                    int* __restrict__ gptr, int n, int G) {
  int i = blockIdx.x * 256 + threadIdx.x;
  if (i >= n) return;
  int b = batch[i];
  if (i == 0) {
    for (int g = 0; g <= b; ++g) gptr[g] = 0;
  } else {
    int bp = batch[i - 1];
    for (int g = bp + 1; g <= b; ++g) gptr[g] = i;
  }
  if (i == n - 1) {
    for (int g = b + 1; g <= G; ++g) gptr[g] = n;
  }
}

// H[n,128] = X[n,128] @ W[128,128] + bias ; thread = 8 rows x 8 cols, k by 4
__global__ __launch_bounds__(256) void gemm_bias_kernel(
    const float* __restrict__ X, const float* __restrict__ W,
    const float* __restrict__ bias, float* __restrict__ H, int n) {
  int t = threadIdx.x;
  int col0 = (t & 15) * 8;
  int rbase = blockIdx.x * 128 + (t >> 4) * 8;
  const float* xp[8];
#pragma unroll
  for (int r = 0; r < 8; ++r) xp[r] = X + (size_t)min(rbase + r, n - 1) * 128;
  float acc[8][8];
#pragma unroll
  for (int r = 0; r < 8; ++r)
#pragma unroll
    for (int c = 0; c < 8; ++c) acc[r][c] = 0.f;

  for (int k = 0; k < 128; k += 4) {
    float4 xv[8];
#pragma unroll
    for (int r = 0; r < 8; ++r) xv[r] = *(const float4*)(xp[r] + k);
#pragma unroll
    for (int kk = 0; kk < 4; ++kk) {
      const float* wrow = W + (size_t)(k + kk) * 128 + col0;
      float4 wa = *(const float4*)(wrow);
      float4 wb = *(const float4*)(wrow + 4);
#pragma unroll
      for (int r = 0; r < 8; ++r) {
        float xs = ((const float*)&xv[r])[kk];
        acc[r][0] = fmaf(xs, wa.x, acc[r][0]);
        acc[r][1] = fmaf(xs, wa.y, acc[r][1]);
        acc[r][2] = fmaf(xs, wa.z, acc[r][2]);
        acc[r][3] = fmaf(xs, wa.w, acc[r][3]);
        acc[r][4] = fmaf(xs, wb.x, acc[r][4]);
        acc[r][5] = fmaf(xs, wb.y, acc[r][5]);
        acc[r][6] = fmaf(xs, wb.z, acc[r][6]);
        acc[r][7] = fmaf(xs, wb.w, acc[r][7]);
      }
    }
  }
  float4 ba = *(const float4*)(bias + col0);
  float4 bb = *(const float4*)(bias + col0 + 4);
#pragma unroll
  for (int r = 0; r < 8; ++r) {
    int row = rbase + r;
    if (row < n) {
      float4 o0 = {acc[r][0] + ba.x, acc[r][1] + ba.y, acc[r][2] + ba.z, acc[r][3] + ba.w};
      float4 o1 = {acc[r][4] + bb.x, acc[r][5] + bb.y, acc[r][6] + bb.z, acc[r][7] + bb.w};
      *(float4*)(H + (size_t)row * 128 + col0) = o0;
      *(float4*)(H + (size_t)row * 128 + col0 + 4) = o1;
    }
  }
}

// Aggregate: HALF-wave (32 lanes) per node, lane = 4 channels (float4).
// Guarded 8-deep unroll: up to 16 independent gathers in flight per wave,
// zero wasted loads, normal (cache-allocating) loads.
__global__ __launch_bounds__(256) void aggregate_kernel(
    const float* __restrict__ H, const int* __restrict__ ptr,
    const int2* __restrict__ emeta, float* __restrict__ Xout, int n) {
  int node = blockIdx.x * 8 + (threadIdx.x >> 5);
  if (node >= n) return;
  int hl = threadIdx.x & 31;
  int beg = ptr[node], end = ptr[node + 1];
  f32x4 a0 = 0.f, a1 = 0.f, a2 = 0.f, a3 = 0.f;
  f32x4 a4 = 0.f, a5 = 0.f, a6 = 0.f, a7 = 0.f;
  const f32x4* Hc = (const f32x4*)(H + hl * 4);
  for (int base = beg; base < end; base += 32) {
    int m = end - base;
    if (m > 32) m = 32;
    int idx = base + hl;
    int2 mv = (hl < m) ? emeta[idx] : make_int2(0, 0);
    int sl = mv.x;
    float nl = __int_as_float(mv.y);
    int j = 0;
    for (; j + 7 < m; j += 8) {
      int s0 = __shfl(sl, j + 0, 32), s1 = __shfl(sl, j + 1, 32);
      int s2 = __shfl(sl, j + 2, 32), s3 = __shfl(sl, j + 3, 32);
      int s4 = __shfl(sl, j + 4, 32), s5 = __shfl(sl, j + 5, 32);
      int s6 = __shfl(sl, j + 6, 32), s7 = __shfl(sl, j + 7, 32);
      float n0 = __shfl(nl, j + 0, 32), n1 = __shfl(nl, j + 1, 32);
      float n2 = __shfl(nl, j + 2, 32), n3 = __shfl(nl, j + 3, 32);
      float n4 = __shfl(nl, j + 4, 32), n5 = __shfl(nl, j + 5, 32);
      float n6 = __shfl(nl, j + 6, 32), n7 = __shfl(nl, j + 7, 32);
      f32x4 h0 = Hc[(size_t)s0 * 32];
      f32x4 h1 = Hc[(size_t)s1 * 32];
      f32x4 h2 = Hc[(size_t)s2 * 32];
      f32x4 h3 = Hc[(size_t)s3 * 32];
      f32x4 h4 = Hc[(size_t)s4 * 32];
      f32x4 h5 = Hc[(size_t)s5 * 32];
      f32x4 h6 = Hc[(size_t)s6 * 32];
      f32x4 h7 = Hc[(size_t)s7 * 32];
      a0 += h0 * n0; a1 += h1 * n1; a2 += h2 * n2; a3 += h3 * n3;
      a4 += h4 * n4; a5 += h5 * n5; a6 += h6 * n6; a7 += h7 * n7;
    }
    for (; j + 3 < m; j += 4) {
      int s0 = __shfl(sl, j + 0, 32), s1 = __shfl(sl, j + 1, 32);
      int s2 = __shfl(sl, j + 2, 32), s3 = __shfl(sl, j + 3, 32);
      float n0 = __shfl(nl, j + 0, 32), n1 = __shfl(nl, j + 1, 32);
      float n2 = __shfl(nl, j + 2, 32), n3 = __shfl(nl, j + 3, 32);
      f32x4 h0 = Hc[(size_t)s0 * 32];
      f32x4 h1 = Hc[(size_t)s1 * 32];
      f32x4 h2 = Hc[(size_t)s2 * 32];
      f32x4 h3 = Hc[(size_t)s3 * 32];
      a0 += h0 * n0; a1 += h1 * n1; a2 += h2 * n2; a3 += h3 * n3;
    }
    for (; j < m; ++j) {
      int s0 = __shfl(sl, j, 32);
      float n0 = __shfl(nl, j, 32);
      f32x4 h0 = Hc[(size_t)s0 * 32];
      a0 += h0 * n0;
    }
  }
  f32x4 s = ((a0 + a1) + (a2 + a3)) + ((a4 + a5) + (a6 + a7));
  f32x4 o;
  o.x = fmaxf(s.x, 0.f);
  o.y = fmaxf(s.y, 0.f);
  o.z = fmaxf(s.z, 0.f);
  o.w = fmaxf(s.w, 0.f);
  *(f32x4*)(Xout + (size_t)node * 128 + hl * 4) = o;
}

// Pool (segment-mean over sorted batch, atomic-free) + MLP head, fused.
__global__ __launch_bounds__(128) void pool_head_kernel(
    const float* __restrict__ X, const int* __restrict__ gptr,
    const float* __restrict__ Wp1, const float* __restrict__ bp1,
    const float* __restrict__ Wp2, const float* __restrict__ bp2,
    float* __restrict__ out, int G) {
  int g = blockIdx.x;
  int j = threadIdx.x;
  int beg = gptr[g], end = gptr[g + 1];
  __shared__ float ps[128];
  __shared__ float hs[128];
  float s0 = 0.f, s1 = 0.f, s2 = 0.f, s3 = 0.f;
  int i = beg;
  for (; i + 3 < end; i += 4) {
    s0 += X[(size_t)i * 128 + j];
    s1 += X[(size_t)(i + 1) * 128 + j];
    s2 += X[(size_t)(i + 2) * 128 + j];
    s3 += X[(size_t)(i + 3) * 128 + j];
  }
  for (; i < end; ++i) s0 += X[(size_t)i * 128 + j];
  float inv = 1.0f / (float)max(end - beg, 1);
  ps[j] = ((s0 + s1) + (s2 + s3)) * inv;
  __syncthreads();
  float acc = bp1[j];
#pragma unroll 8
  for (int k = 0; k < 128; ++k) acc = fmaf(ps[k], Wp1[k * 128 + j], acc);
  hs[j] = fmaxf(acc, 0.f) * Wp2[j];
  __syncthreads();
  for (int off = 64; off > 0; off >>= 1) {
    if (j < off) hs[j] += hs[j + off];
    __syncthreads();
  }
  if (j == 0) out[g] = hs[0] + bp2[0];
}

extern "C" void kernel_launch(void* const* d_in, const int* in_sizes, int n_in,
                              void* d_out, int out_size, void* d_ws, size_t ws_size,
                              hipStream_t stream) {
  const float* x    = (const float*)d_in[0];
  const int*   eidx = (const int*)d_in[1];
  const int*   batch= (const int*)d_in[2];
  const float* W0 = (const float*)d_in[3];
  const float* b0 = (const float*)d_in[4];
  const float* W1 = (const float*)d_in[5];
  const float* b1 = (const float*)d_in[6];
  const float* W2 = (const float*)d_in[7];
  const float* b2 = (const float*)d_in[8];
  const float* Wp1 = (const float*)d_in[9];
  const float* bp1 = (const float*)d_in[10];
  const float* Wp2 = (const float*)d_in[11];
  const float* bp2 = (const float*)d_in[12];
  float* out = (float*)d_out;

  const int N = in_sizes[0] / 128;
  const int E = in_sizes[1] / 2;
  const int G = out_size;
  const int M = E + N;
  const int T = (N + 1023) / 1024;  // #scan tiles; N<=131072 keeps T<=128

  const int* src = eidx;
  const int* dst = eidx + E;

  char* ws = (char*)d_ws;
  size_t off = 0;
  auto alloc = [&](size_t bytes) -> void* {
    void* p = ws + off;
    off = (off + bytes + 255) & ~(size_t)255;
    return p;
  };
  int*   indeg   = (int*)  alloc((size_t)N * 4);
  int*   ptr     = (int*)  alloc((size_t)(N + 1) * 4);
  int*   cursor  = (int*)  alloc((size_t)N * 4);
  int2*  emeta   = (int2*) alloc((size_t)M * 8);
  float* bufH    = (float*)alloc((size_t)N * 128 * 4);
  float* bufX    = (float*)alloc((size_t)N * 128 * 4);
  int*   gptr    = (int*)  alloc((size_t)(G + 1) * 4);
  int*   tilesum = (int*)  alloc((size_t)T * 4);
  int*   tileoff = (int*)  alloc((size_t)T * 4);
  (void)ws_size;

  hipMemsetAsync(indeg,  0, (size_t)N * 4, stream);
  hipMemsetAsync(cursor, 0, (size_t)N * 4, stream);

  count_deg_kernel<<<(E + 255) / 256, 256, 0, stream>>>(dst, indeg, E);
  tile_reduce_kernel<<<T, 1024, 0, stream>>>(indeg, tilesum, N);
  scan_tiles_kernel<<<1, 128, 0, stream>>>(tilesum, tileoff, ptr + N, T);
  scan_emit_kernel<<<T, 1024, 0, stream>>>(indeg, tileoff, ptr, N);
  fill_edges_kernel<<<(E + 255) / 256, 256, 0, stream>>>(src, dst, indeg, ptr, cursor, emeta, E);
  fill_self_kernel<<<(N + 255) / 256, 256, 0, stream>>>(indeg, ptr, cursor, emeta, N);
  graph_bounds_kernel<<<(N + 255) / 256, 256, 0, stream>>>(batch, gptr, N, G);

  dim3 gemm_grid((N + 127) / 128);
  dim3 agg_grid((N + 7) / 8);

  gemm_bias_kernel<<<gemm_grid, 256, 0, stream>>>(x,    W0, b0, bufH, N);
  aggregate_kernel<<<agg_grid, 256, 0, stream>>>(bufH, ptr, emeta, bufX, N);
  gemm_bias_kernel<<<gemm_grid, 256, 0, stream>>>(bufX, W1, b1, bufH, N);
  aggregate_kernel<<<agg_grid, 256, 0, stream>>>(bufH, ptr, emeta, bufX, N);
  gemm_bias_kernel<<<gemm_grid, 256, 0, stream>>>(bufX, W2, b2, bufH, N);
  aggregate_kernel<<<agg_grid, 256, 0, stream>>>(bufH, ptr, emeta, bufX, N);

  pool_head_kernel<<<G, 128, 0, stream>>>(bufX, gptr, Wp1, bp1, Wp2, bp2, out, G);
}

// Round 6
// 852.345 us; speedup vs baseline: 1.2359x; 1.0030x over previous
//
#include <hip/hip_runtime.h>
#include <hip/hip_bf16.h>
#include <math.h>

// ---------------------------------------------------------------------------
// GCN GraphRegressor: 3x (linear -> gather*norm -> scatter-sum -> relu)
//                     -> segment-mean pool -> MLP head
// R6: aggregate = persistent half-waves (grid-stride nodes) with next-node
//     ptr prefetch; guarded 8-deep float4 gather unroll (16 in flight/wave).
//     GEMM = 8x8/thread with explicit next-k-chunk X prefetch.
//     fill_edges+fill_self merged. Pool = atomic-free segmented + head.
// Known floors (measured): aggregate FETCH ~= 8 XCD x 51MB H = compulsory
// per-XCD L2 fill for random gather; ~20 rows in flight/CU sustained.
// ---------------------------------------------------------------------------

typedef float f32x4 __attribute__((ext_vector_type(4)));

__global__ void count_deg_kernel(const int* __restrict__ dst, int* __restrict__ indeg, int E) {
  int e = blockIdx.x * 256 + threadIdx.x;
  if (e < E) atomicAdd(&indeg[dst[e]], 1);
}

// ---- 3-phase exclusive scan of (indeg[i]+1) into ptr[0..n] ----------------
__global__ __launch_bounds__(1024) void tile_reduce_kernel(
    const int* __restrict__ indeg, int* __restrict__ tilesum, int n) {
  __shared__ int ws[16];
  int i = blockIdx.x * 1024 + threadIdx.x;
  int v = (i < n) ? (indeg[i] + 1) : 0;
  for (int off = 32; off > 0; off >>= 1) v += __shfl_down(v, off);
  int wid = threadIdx.x >> 6, lane = threadIdx.x & 63;
  if (lane == 0) ws[wid] = v;
  __syncthreads();
  if (threadIdx.x == 0) {
    int s = 0;
    for (int w = 0; w < 16; ++w) s += ws[w];
    tilesum[blockIdx.x] = s;
  }
}

__global__ __launch_bounds__(128) void scan_tiles_kernel(
    const int* __restrict__ tilesum, int* __restrict__ tileoff,
    int* __restrict__ ptr_last, int T) {
  __shared__ int sm[128];
  int v = (threadIdx.x < T) ? tilesum[threadIdx.x] : 0;
  sm[threadIdx.x] = v;
  __syncthreads();
  for (int off = 1; off < 128; off <<= 1) {
    int t = (threadIdx.x >= off) ? sm[threadIdx.x - off] : 0;
    __syncthreads();
    sm[threadIdx.x] += t;
    __syncthreads();
  }
  if (threadIdx.x < T) tileoff[threadIdx.x] = sm[threadIdx.x] - v;
  if (threadIdx.x == 127) *ptr_last = sm[127];
}

__global__ __launch_bounds__(1024) void scan_emit_kernel(
    const int* __restrict__ indeg, const int* __restrict__ tileoff,
    int* __restrict__ ptr, int n) {
  __shared__ int wsum[16];
  int i = blockIdx.x * 1024 + threadIdx.x;
  int v = (i < n) ? (indeg[i] + 1) : 0;
  int lane = threadIdx.x & 63, wid = threadIdx.x >> 6;
  int x = v;
  for (int off = 1; off < 64; off <<= 1) {
    int y = __shfl_up(x, off);
    if (lane >= off) x += y;
  }
  if (lane == 63) wsum[wid] = x;
  __syncthreads();
  if (threadIdx.x == 0) {
    int run = 0;
    for (int w = 0; w < 16; ++w) { int t = wsum[w]; wsum[w] = run; run += t; }
  }
  __syncthreads();
  if (i < n) ptr[i] = x - v + wsum[wid] + tileoff[blockIdx.x];
}

// merged edge + self-loop CSR fill
__global__ void fill_all_kernel(const int* __restrict__ src, const int* __restrict__ dst,
                                const int* __restrict__ indeg, const int* __restrict__ ptr,
                                int* __restrict__ cursor, int2* __restrict__ emeta,
                                int E, int n) {
  int i = blockIdx.x * 256 + threadIdx.x;
  if (i < E) {
    int s = src[i], d = dst[i];
    int pos = ptr[d] + atomicAdd(&cursor[d], 1);
    float dd = (float)(indeg[s] + 1) * (float)(indeg[d] + 1);
    emeta[pos] = make_int2(s, __float_as_int(1.0f / sqrtf(dd)));
  } else if (i < E + n) {
    int v = i - E;
    int pos = ptr[v] + atomicAdd(&cursor[v], 1);
    emeta[pos] = make_int2(v, __float_as_int(1.0f / (float)(indeg[v] + 1)));
  }
}

// graph boundaries from sorted batch: gptr[g] = first node with batch >= g
__global__ void graph_bounds_kernel(const int* __restrict__ batch,
                                    int* __restrict__ gptr, int n, int G) {
  int i = blockIdx.x * 256 + threadIdx.x;
  if (i >= n) return;
  int b = batch[i];
  if (i == 0) {
    for (int g = 0; g <= b; ++g) gptr[g] = 0;
  } else {
    int bp = batch[i - 1];
    for (int g = bp + 1; g <= b; ++g) gptr[g] = i;
  }
  if (i == n - 1) {
    for (int g = b + 1; g <= G; ++g) gptr[g] = n;
  }
}

// H[n,128] = X[n,128] @ W[128,128] + bias ; thread = 8 rows x 8 cols,
// k by 4 with explicit next-chunk X prefetch (software pipeline).
__global__ __launch_bounds__(256) void gemm_bias_kernel(
    const float* __restrict__ X, const float* __restrict__ W,
    const float* __restrict__ bias, float* __restrict__ H, int n) {
  int t = threadIdx.x;
  int col0 = (t & 15) * 8;
  int rbase = blockIdx.x * 128 + (t >> 4) * 8;
  const float* xp[8];
#pragma unroll
  for (int r = 0; r < 8; ++r) xp[r] = X + (size_t)min(rbase + r, n - 1) * 128;
  float acc[8][8];
#pragma unroll
  for (int r = 0; r < 8; ++r)
#pragma unroll
    for (int c = 0; c < 8; ++c) acc[r][c] = 0.f;

  float4 xv[8];
#pragma unroll
  for (int r = 0; r < 8; ++r) xv[r] = *(const float4*)(xp[r]);

  auto fma_chunk = [&](int k) {
#pragma unroll
    for (int kk = 0; kk < 4; ++kk) {
      const float* wrow = W + (size_t)(k + kk) * 128 + col0;
      float4 wa = *(const float4*)(wrow);
      float4 wb = *(const float4*)(wrow + 4);
#pragma unroll
      for (int r = 0; r < 8; ++r) {
        float xs = ((const float*)&xv[r])[kk];
        acc[r][0] = fmaf(xs, wa.x, acc[r][0]);
        acc[r][1] = fmaf(xs, wa.y, acc[r][1]);
        acc[r][2] = fmaf(xs, wa.z, acc[r][2]);
        acc[r][3] = fmaf(xs, wa.w, acc[r][3]);
        acc[r][4] = fmaf(xs, wb.x, acc[r][4]);
        acc[r][5] = fmaf(xs, wb.y, acc[r][5]);
        acc[r][6] = fmaf(xs, wb.z, acc[r][6]);
        acc[r][7] = fmaf(xs, wb.w, acc[r][7]);
      }
    }
  };

  for (int kc = 0; kc < 31; ++kc) {
    int k = kc * 4;
    float4 xn[8];
#pragma unroll
    for (int r = 0; r < 8; ++r) xn[r] = *(const float4*)(xp[r] + k + 4);
    fma_chunk(k);
#pragma unroll
    for (int r = 0; r < 8; ++r) xv[r] = xn[r];
  }
  fma_chunk(124);

  float4 ba = *(const float4*)(bias + col0);
  float4 bb = *(const float4*)(bias + col0 + 4);
#pragma unroll
  for (int r = 0; r < 8; ++r) {
    int row = rbase + r;
    if (row < n) {
      float4 o0 = {acc[r][0] + ba.x, acc[r][1] + ba.y, acc[r][2] + ba.z, acc[r][3] + ba.w};
      float4 o1 = {acc[r][4] + bb.x, acc[r][5] + bb.y, acc[r][6] + bb.z, acc[r][7] + bb.w};
      *(float4*)(H + (size_t)row * 128 + col0) = o0;
      *(float4*)(H + (size_t)row * 128 + col0 + 4) = o1;
    }
  }
}

// Aggregate: persistent HALF-wave (32 lanes) per node, grid-stride over
// nodes; next node's ptr loads issued before the current gather loop.
// Guarded 8-deep unroll, normal cache-allocating float4 gathers.
__global__ __launch_bounds__(256) void aggregate_kernel(
    const float* __restrict__ H, const int* __restrict__ ptr,
    const int2* __restrict__ emeta, float* __restrict__ Xout,
    int n, int stride) {
  int hw = blockIdx.x * 8 + (threadIdx.x >> 5);
  int hl = threadIdx.x & 31;
  const f32x4* Hc = (const f32x4*)(H + hl * 4);
  int node = hw;
  int beg = 0, end = 0;
  if (node < n) { beg = ptr[node]; end = ptr[node + 1]; }
  while (node < n) {
    int nnode = node + stride;
    int nbeg = 0, nend = 0;
    if (nnode < n) { nbeg = ptr[nnode]; nend = ptr[nnode + 1]; }

    f32x4 a0 = 0.f, a1 = 0.f, a2 = 0.f, a3 = 0.f;
    f32x4 a4 = 0.f, a5 = 0.f, a6 = 0.f, a7 = 0.f;
    for (int base = beg; base < end; base += 32) {
      int m = end - base;
      if (m > 32) m = 32;
      int idx = base + hl;
      int2 mv = (hl < m) ? emeta[idx] : make_int2(0, 0);
      int sl = mv.x;
      float nl = __int_as_float(mv.y);
      int j = 0;
      for (; j + 7 < m; j += 8) {
        int s0 = __shfl(sl, j + 0, 32), s1 = __shfl(sl, j + 1, 32);
        int s2 = __shfl(sl, j + 2, 32), s3 = __shfl(sl, j + 3, 32);
        int s4 = __shfl(sl, j + 4, 32), s5 = __shfl(sl, j + 5, 32);
        int s6 = __shfl(sl, j + 6, 32), s7 = __shfl(sl, j + 7, 32);
        float n0 = __shfl(nl, j + 0, 32), n1 = __shfl(nl, j + 1, 32);
        float n2 = __shfl(nl, j + 2, 32), n3 = __shfl(nl, j + 3, 32);
        float n4 = __shfl(nl, j + 4, 32), n5 = __shfl(nl, j + 5, 32);
        float n6 = __shfl(nl, j + 6, 32), n7 = __shfl(nl, j + 7, 32);
        f32x4 h0 = Hc[(size_t)s0 * 32];
        f32x4 h1 = Hc[(size_t)s1 * 32];
        f32x4 h2 = Hc[(size_t)s2 * 32];
        f32x4 h3 = Hc[(size_t)s3 * 32];
        f32x4 h4 = Hc[(size_t)s4 * 32];
        f32x4 h5 = Hc[(size_t)s5 * 32];
        f32x4 h6 = Hc[(size_t)s6 * 32];
        f32x4 h7 = Hc[(size_t)s7 * 32];
        a0 += h0 * n0; a1 += h1 * n1; a2 += h2 * n2; a3 += h3 * n3;
        a4 += h4 * n4; a5 += h5 * n5; a6 += h6 * n6; a7 += h7 * n7;
      }
      for (; j + 3 < m; j += 4) {
        int s0 = __shfl(sl, j + 0, 32), s1 = __shfl(sl, j + 1, 32);
        int s2 = __shfl(sl, j + 2, 32), s3 = __shfl(sl, j + 3, 32);
        float n0 = __shfl(nl, j + 0, 32), n1 = __shfl(nl, j + 1, 32);
        float n2 = __shfl(nl, j + 2, 32), n3 = __shfl(nl, j + 3, 32);
        f32x4 h0 = Hc[(size_t)s0 * 32];
        f32x4 h1 = Hc[(size_t)s1 * 32];
        f32x4 h2 = Hc[(size_t)s2 * 32];
        f32x4 h3 = Hc[(size_t)s3 * 32];
        a0 += h0 * n0; a1 += h1 * n1; a2 += h2 * n2; a3 += h3 * n3;
      }
      for (; j < m; ++j) {
        int s0 = __shfl(sl, j, 32);
        float n0 = __shfl(nl, j, 32);
        f32x4 h0 = Hc[(size_t)s0 * 32];
        a0 += h0 * n0;
      }
    }
    f32x4 s = ((a0 + a1) + (a2 + a3)) + ((a4 + a5) + (a6 + a7));
    f32x4 o;
    o.x = fmaxf(s.x, 0.f);
    o.y = fmaxf(s.y, 0.f);
    o.z = fmaxf(s.z, 0.f);
    o.w = fmaxf(s.w, 0.f);
    *(f32x4*)(Xout + (size_t)node * 128 + hl * 4) = o;

    node = nnode; beg = nbeg; end = nend;
  }
}

// Pool (segment-mean over sorted batch, atomic-free) + MLP head, fused.
__global__ __launch_bounds__(128) void pool_head_kernel(
    const float* __restrict__ X, const int* __restrict__ gptr,
    const float* __restrict__ Wp1, const float* __restrict__ bp1,
    const float* __restrict__ Wp2, const float* __restrict__ bp2,
    float* __restrict__ out, int G) {
  int g = blockIdx.x;
  int j = threadIdx.x;
  int beg = gptr[g], end = gptr[g + 1];
  __shared__ float ps[128];
  __shared__ float hs[128];
  float s0 = 0.f, s1 = 0.f, s2 = 0.f, s3 = 0.f;
  int i = beg;
  for (; i + 3 < end; i += 4) {
    s0 += X[(size_t)i * 128 + j];
    s1 += X[(size_t)(i + 1) * 128 + j];
    s2 += X[(size_t)(i + 2) * 128 + j];
    s3 += X[(size_t)(i + 3) * 128 + j];
  }
  for (; i < end; ++i) s0 += X[(size_t)i * 128 + j];
  float inv = 1.0f / (float)max(end - beg, 1);
  ps[j] = ((s0 + s1) + (s2 + s3)) * inv;
  __syncthreads();
  float acc = bp1[j];
#pragma unroll 8
  for (int k = 0; k < 128; ++k) acc = fmaf(ps[k], Wp1[k * 128 + j], acc);
  hs[j] = fmaxf(acc, 0.f) * Wp2[j];
  __syncthreads();
  for (int off = 64; off > 0; off >>= 1) {
    if (j < off) hs[j] += hs[j + off];
    __syncthreads();
  }
  if (j == 0) out[g] = hs[0] + bp2[0];
}

extern "C" void kernel_launch(void* const* d_in, const int* in_sizes, int n_in,
                              void* d_out, int out_size, void* d_ws, size_t ws_size,
                              hipStream_t stream) {
  const float* x    = (const float*)d_in[0];
  const int*   eidx = (const int*)d_in[1];
  const int*   batch= (const int*)d_in[2];
  const float* W0 = (const float*)d_in[3];
  const float* b0 = (const float*)d_in[4];
  const float* W1 = (const float*)d_in[5];
  const float* b1 = (const float*)d_in[6];
  const float* W2 = (const float*)d_in[7];
  const float* b2 = (const float*)d_in[8];
  const float* Wp1 = (const float*)d_in[9];
  const float* bp1 = (const float*)d_in[10];
  const float* Wp2 = (const float*)d_in[11];
  const float* bp2 = (const float*)d_in[12];
  float* out = (float*)d_out;

  const int N = in_sizes[0] / 128;
  const int E = in_sizes[1] / 2;
  const int G = out_size;
  const int M = E + N;
  const int T = (N + 1023) / 1024;  // #scan tiles; N<=131072 keeps T<=128

  const int* src = eidx;
  const int* dst = eidx + E;

  char* ws = (char*)d_ws;
  size_t off = 0;
  auto alloc = [&](size_t bytes) -> void* {
    void* p = ws + off;
    off = (off + bytes + 255) & ~(size_t)255;
    return p;
  };
  int*   indeg   = (int*)  alloc((size_t)N * 4);
  int*   ptr     = (int*)  alloc((size_t)(N + 1) * 4);
  int*   cursor  = (int*)  alloc((size_t)N * 4);
  int2*  emeta   = (int2*) alloc((size_t)M * 8);
  float* bufH    = (float*)alloc((size_t)N * 128 * 4);
  float* bufX    = (float*)alloc((size_t)N * 128 * 4);
  int*   gptr    = (int*)  alloc((size_t)(G + 1) * 4);
  int*   tilesum = (int*)  alloc((size_t)T * 4);
  int*   tileoff = (int*)  alloc((size_t)T * 4);
  (void)ws_size;

  hipMemsetAsync(indeg,  0, (size_t)N * 4, stream);
  hipMemsetAsync(cursor, 0, (size_t)N * 4, stream);

  count_deg_kernel<<<(E + 255) / 256, 256, 0, stream>>>(dst, indeg, E);
  tile_reduce_kernel<<<T, 1024, 0, stream>>>(indeg, tilesum, N);
  scan_tiles_kernel<<<1, 128, 0, stream>>>(tilesum, tileoff, ptr + N, T);
  scan_emit_kernel<<<T, 1024, 0, stream>>>(indeg, tileoff, ptr, N);
  fill_all_kernel<<<(E + N + 255) / 256, 256, 0, stream>>>(src, dst, indeg, ptr, cursor, emeta, E, N);
  graph_bounds_kernel<<<(N + 255) / 256, 256, 0, stream>>>(batch, gptr, N, G);

  dim3 gemm_grid((N + 127) / 128);
  const int agg_blocks = 2048;           // persistent: 16384 half-waves
  const int agg_stride = agg_blocks * 8; // nodes advance by total half-waves

  gemm_bias_kernel<<<gemm_grid, 256, 0, stream>>>(x,    W0, b0, bufH, N);
  aggregate_kernel<<<agg_blocks, 256, 0, stream>>>(bufH, ptr, emeta, bufX, N, agg_stride);
  gemm_bias_kernel<<<gemm_grid, 256, 0, stream>>>(bufX, W1, b1, bufH, N);
  aggregate_kernel<<<agg_blocks, 256, 0, stream>>>(bufH, ptr, emeta, bufX, N, agg_stride);
  gemm_bias_kernel<<<gemm_grid, 256, 0, stream>>>(bufX, W2, b2, bufH, N);
  aggregate_kernel<<<agg_blocks, 256, 0, stream>>>(bufH, ptr, emeta, bufX, N, agg_stride);

  pool_head_kernel<<<G, 128, 0, stream>>>(bufX, gptr, Wp1, bp1, Wp2, bp2, out, G);
}

// Round 7
// 733.039 us; speedup vs baseline: 1.4371x; 1.1628x over previous
//
#include <hip/hip_runtime.h>
#include <hip/hip_bf16.h>
#include <math.h>

// ---------------------------------------------------------------------------
// GCN GraphRegressor: 3x (linear -> gather*norm -> scatter-sum -> relu)
//                     -> segment-mean pool -> MLP head
// R7: GEMM via MFMA bf16 3-split (xh*Wh + xl*Wh + xh*Wl), W pre-split into
//     fragment-layout arrays. Aggregate reverted to R5 flat form (persistent
//     variant regressed: occupancy 57->50%). CSR fill merged; pool atomic-free.
// Floors (measured): aggregate FETCH 402MB = 100K rows x 512B x 8 XCD =
// compulsory per-XCD fill; ~3.9 TB/s L2-miss BW -> ~105us/aggregate floor.
// ---------------------------------------------------------------------------

typedef float f32x4 __attribute__((ext_vector_type(4)));
typedef short s16x8 __attribute__((ext_vector_type(8)));

__device__ __forceinline__ unsigned short f2bf(float x) {
  unsigned u = __float_as_uint(x);
  unsigned r = (u + 0x7FFFu + ((u >> 16) & 1u)) >> 16;
  return (unsigned short)r;
}

__global__ void count_deg_kernel(const int* __restrict__ dst, int* __restrict__ indeg, int E) {
  int e = blockIdx.x * 256 + threadIdx.x;
  if (e < E) atomicAdd(&indeg[dst[e]], 1);
}

// ---- 3-phase exclusive scan of (indeg[i]+1) into ptr[0..n] ----------------
__global__ __launch_bounds__(1024) void tile_reduce_kernel(
    const int* __restrict__ indeg, int* __restrict__ tilesum, int n) {
  __shared__ int ws[16];
  int i = blockIdx.x * 1024 + threadIdx.x;
  int v = (i < n) ? (indeg[i] + 1) : 0;
  for (int off = 32; off > 0; off >>= 1) v += __shfl_down(v, off);
  int wid = threadIdx.x >> 6, lane = threadIdx.x & 63;
  if (lane == 0) ws[wid] = v;
  __syncthreads();
  if (threadIdx.x == 0) {
    int s = 0;
    for (int w = 0; w < 16; ++w) s += ws[w];
    tilesum[blockIdx.x] = s;
  }
}

__global__ __launch_bounds__(128) void scan_tiles_kernel(
    const int* __restrict__ tilesum, int* __restrict__ tileoff,
    int* __restrict__ ptr_last, int T) {
  __shared__ int sm[128];
  int v = (threadIdx.x < T) ? tilesum[threadIdx.x] : 0;
  sm[threadIdx.x] = v;
  __syncthreads();
  for (int off = 1; off < 128; off <<= 1) {
    int t = (threadIdx.x >= off) ? sm[threadIdx.x - off] : 0;
    __syncthreads();
    sm[threadIdx.x] += t;
    __syncthreads();
  }
  if (threadIdx.x < T) tileoff[threadIdx.x] = sm[threadIdx.x] - v;
  if (threadIdx.x == 127) *ptr_last = sm[127];
}

__global__ __launch_bounds__(1024) void scan_emit_kernel(
    const int* __restrict__ indeg, const int* __restrict__ tileoff,
    int* __restrict__ ptr, int n) {
  __shared__ int wsum[16];
  int i = blockIdx.x * 1024 + threadIdx.x;
  int v = (i < n) ? (indeg[i] + 1) : 0;
  int lane = threadIdx.x & 63, wid = threadIdx.x >> 6;
  int x = v;
  for (int off = 1; off < 64; off <<= 1) {
    int y = __shfl_up(x, off);
    if (lane >= off) x += y;
  }
  if (lane == 63) wsum[wid] = x;
  __syncthreads();
  if (threadIdx.x == 0) {
    int run = 0;
    for (int w = 0; w < 16; ++w) { int t = wsum[w]; wsum[w] = run; run += t; }
  }
  __syncthreads();
  if (i < n) ptr[i] = x - v + wsum[wid] + tileoff[blockIdx.x];
}

// merged edge + self-loop CSR fill
__global__ void fill_all_kernel(const int* __restrict__ src, const int* __restrict__ dst,
                                const int* __restrict__ indeg, const int* __restrict__ ptr,
                                int* __restrict__ cursor, int2* __restrict__ emeta,
                                int E, int n) {
  int i = blockIdx.x * 256 + threadIdx.x;
  if (i < E) {
    int s = src[i], d = dst[i];
    int pos = ptr[d] + atomicAdd(&cursor[d], 1);
    float dd = (float)(indeg[s] + 1) * (float)(indeg[d] + 1);
    emeta[pos] = make_int2(s, __float_as_int(1.0f / sqrtf(dd)));
  } else if (i < E + n) {
    int v = i - E;
    int pos = ptr[v] + atomicAdd(&cursor[v], 1);
    emeta[pos] = make_int2(v, __float_as_int(1.0f / (float)(indeg[v] + 1)));
  }
}

// graph boundaries from sorted batch: gptr[g] = first node with batch >= g
__global__ void graph_bounds_kernel(const int* __restrict__ batch,
                                    int* __restrict__ gptr, int n, int G) {
  int i = blockIdx.x * 256 + threadIdx.x;
  if (i >= n) return;
  int b = batch[i];
  if (i == 0) {
    for (int g = 0; g <= b; ++g) gptr[g] = 0;
  } else {
    int bp = batch[i - 1];
    for (int g = bp + 1; g <= b; ++g) gptr[g] = i;
  }
  if (i == n - 1) {
    for (int g = b + 1; g <= G; ++g) gptr[g] = n;
  }
}

// Split W[128x128] fp32 into bf16 hi/lo in MFMA B-fragment layout:
// frag index i = ((ntile*4 + kstep)*64 + lane)*8 + j maps to
// k = kstep*32 + (lane>>4)*8 + j ; n = ntile*16 + (lane&15)
__global__ __launch_bounds__(256) void wsplit_kernel(
    const float* __restrict__ W, short* __restrict__ Whi, short* __restrict__ Wlo) {
  int i = blockIdx.x * 256 + threadIdx.x;
  if (i >= 16384) return;
  int j = i & 7, lane = (i >> 3) & 63, ks = (i >> 9) & 3, nt = i >> 11;
  int k = ks * 32 + (lane >> 4) * 8 + j;
  int nn = nt * 16 + (lane & 15);
  float w = W[k * 128 + nn];
  unsigned short h = f2bf(w);
  float hf = __uint_as_float(((unsigned)h) << 16);
  Whi[i] = (short)h;
  Wlo[i] = (short)f2bf(w - hf);
}

// H[n,128] = X[n,128] @ W[128,128] + bias via 3x bf16-split MFMA.
// 256 threads = 4 waves; wave computes a 16(M) x 128(N) strip, K=128.
// A layout: A[m=lane&15][k=quad*8+j] ; C/D: col=lane&15, row=quad*4+reg.
__global__ __launch_bounds__(256) void gemm_mfma_kernel(
    const float* __restrict__ X, const short* __restrict__ Whi,
    const short* __restrict__ Wlo, const float* __restrict__ bias,
    float* __restrict__ H, int n) {
  int wave = threadIdx.x >> 6, lane = threadIdx.x & 63;
  int quad = lane >> 4, m = lane & 15;
  int mbase = blockIdx.x * 64 + wave * 16;
  int row = min(mbase + m, n - 1);
  const float* xr = X + (size_t)row * 128 + quad * 8;
  const s16x8* WH = (const s16x8*)Whi;
  const s16x8* WL = (const s16x8*)Wlo;

  f32x4 acc[8];
#pragma unroll
  for (int nt = 0; nt < 8; ++nt) acc[nt] = 0.f;

#pragma unroll
  for (int ks = 0; ks < 4; ++ks) {
    float4 xa = *(const float4*)(xr + ks * 32);
    float4 xb = *(const float4*)(xr + ks * 32 + 4);
    float xs[8] = {xa.x, xa.y, xa.z, xa.w, xb.x, xb.y, xb.z, xb.w};
    s16x8 ah, al;
#pragma unroll
    for (int j = 0; j < 8; ++j) {
      unsigned short h = f2bf(xs[j]);
      float hf = __uint_as_float(((unsigned)h) << 16);
      ah[j] = (short)h;
      al[j] = (short)f2bf(xs[j] - hf);
    }
#pragma unroll
    for (int nt = 0; nt < 8; ++nt) {
      s16x8 wh = WH[(nt * 4 + ks) * 64 + lane];
      s16x8 wl = WL[(nt * 4 + ks) * 64 + lane];
      acc[nt] = __builtin_amdgcn_mfma_f32_16x16x32_bf16(ah, wh, acc[nt], 0, 0, 0);
      acc[nt] = __builtin_amdgcn_mfma_f32_16x16x32_bf16(al, wh, acc[nt], 0, 0, 0);
      acc[nt] = __builtin_amdgcn_mfma_f32_16x16x32_bf16(ah, wl, acc[nt], 0, 0, 0);
    }
  }

#pragma unroll
  for (int nt = 0; nt < 8; ++nt) {
    int col = nt * 16 + m;
    float b = bias[col];
#pragma unroll
    for (int r = 0; r < 4; ++r) {
      int rr = mbase + quad * 4 + r;
      if (rr < n) H[(size_t)rr * 128 + col] = acc[nt][r] + b;
    }
  }
}

// Aggregate (R5 flat form): HALF-wave (32 lanes) per node, lane = 4 channels.
// Guarded 8-deep unroll: up to 16 independent gathers in flight per wave.
__global__ __launch_bounds__(256) void aggregate_kernel(
    const float* __restrict__ H, const int* __restrict__ ptr,
    const int2* __restrict__ emeta, float* __restrict__ Xout, int n) {
  int node = blockIdx.x * 8 + (threadIdx.x >> 5);
  if (node >= n) return;
  int hl = threadIdx.x & 31;
  int beg = ptr[node], end = ptr[node + 1];
  f32x4 a0 = 0.f, a1 = 0.f, a2 = 0.f, a3 = 0.f;
  f32x4 a4 = 0.f, a5 = 0.f, a6 = 0.f, a7 = 0.f;
  const f32x4* Hc = (const f32x4*)(H + hl * 4);
  for (int base = beg; base < end; base += 32) {
    int m = end - base;
    if (m > 32) m = 32;
    int idx = base + hl;
    int2 mv = (hl < m) ? emeta[idx] : make_int2(0, 0);
    int sl = mv.x;
    float nl = __int_as_float(mv.y);
    int j = 0;
    for (; j + 7 < m; j += 8) {
      int s0 = __shfl(sl, j + 0, 32), s1 = __shfl(sl, j + 1, 32);
      int s2 = __shfl(sl, j + 2, 32), s3 = __shfl(sl, j + 3, 32);
      int s4 = __shfl(sl, j + 4, 32), s5 = __shfl(sl, j + 5, 32);
      int s6 = __shfl(sl, j + 6, 32), s7 = __shfl(sl, j + 7, 32);
      float n0 = __shfl(nl, j + 0, 32), n1 = __shfl(nl, j + 1, 32);
      float n2 = __shfl(nl, j + 2, 32), n3 = __shfl(nl, j + 3, 32);
      float n4 = __shfl(nl, j + 4, 32), n5 = __shfl(nl, j + 5, 32);
      float n6 = __shfl(nl, j + 6, 32), n7 = __shfl(nl, j + 7, 32);
      f32x4 h0 = Hc[(size_t)s0 * 32];
      f32x4 h1 = Hc[(size_t)s1 * 32];
      f32x4 h2 = Hc[(size_t)s2 * 32];
      f32x4 h3 = Hc[(size_t)s3 * 32];
      f32x4 h4 = Hc[(size_t)s4 * 32];
      f32x4 h5 = Hc[(size_t)s5 * 32];
      f32x4 h6 = Hc[(size_t)s6 * 32];
      f32x4 h7 = Hc[(size_t)s7 * 32];
      a0 += h0 * n0; a1 += h1 * n1; a2 += h2 * n2; a3 += h3 * n3;
      a4 += h4 * n4; a5 += h5 * n5; a6 += h6 * n6; a7 += h7 * n7;
    }
    for (; j + 3 < m; j += 4) {
      int s0 = __shfl(sl, j + 0, 32), s1 = __shfl(sl, j + 1, 32);
      int s2 = __shfl(sl, j + 2, 32), s3 = __shfl(sl, j + 3, 32);
      float n0 = __shfl(nl, j + 0, 32), n1 = __shfl(nl, j + 1, 32);
      float n2 = __shfl(nl, j + 2, 32), n3 = __shfl(nl, j + 3, 32);
      f32x4 h0 = Hc[(size_t)s0 * 32];
      f32x4 h1 = Hc[(size_t)s1 * 32];
      f32x4 h2 = Hc[(size_t)s2 * 32];
      f32x4 h3 = Hc[(size_t)s3 * 32];
      a0 += h0 * n0; a1 += h1 * n1; a2 += h2 * n2; a3 += h3 * n3;
    }
    for (; j < m; ++j) {
      int s0 = __shfl(sl, j, 32);
      float n0 = __shfl(nl, j, 32);
      f32x4 h0 = Hc[(size_t)s0 * 32];
      a0 += h0 * n0;
    }
  }
  f32x4 s = ((a0 + a1) + (a2 + a3)) + ((a4 + a5) + (a6 + a7));
  f32x4 o;
  o.x = fmaxf(s.x, 0.f);
  o.y = fmaxf(s.y, 0.f);
  o.z = fmaxf(s.z, 0.f);
  o.w = fmaxf(s.w, 0.f);
  *(f32x4*)(Xout + (size_t)node * 128 + hl * 4) = o;
}

// Pool (segment-mean over sorted batch, atomic-free) + MLP head, fused.
__global__ __launch_bounds__(128) void pool_head_kernel(
    const float* __restrict__ X, const int* __restrict__ gptr,
    const float* __restrict__ Wp1, const float* __restrict__ bp1,
    const float* __restrict__ Wp2, const float* __restrict__ bp2,
    float* __restrict__ out, int G) {
  int g = blockIdx.x;
  int j = threadIdx.x;
  int beg = gptr[g], end = gptr[g + 1];
  __shared__ float ps[128];
  __shared__ float hs[128];
  float s0 = 0.f, s1 = 0.f, s2 = 0.f, s3 = 0.f;
  int i = beg;
  for (; i + 3 < end; i += 4) {
    s0 += X[(size_t)i * 128 + j];
    s1 += X[(size_t)(i + 1) * 128 + j];
    s2 += X[(size_t)(i + 2) * 128 + j];
    s3 += X[(size_t)(i + 3) * 128 + j];
  }
  for (; i < end; ++i) s0 += X[(size_t)i * 128 + j];
  float inv = 1.0f / (float)max(end - beg, 1);
  ps[j] = ((s0 + s1) + (s2 + s3)) * inv;
  __syncthreads();
  float acc = bp1[j];
#pragma unroll 8
  for (int k = 0; k < 128; ++k) acc = fmaf(ps[k], Wp1[k * 128 + j], acc);
  hs[j] = fmaxf(acc, 0.f) * Wp2[j];
  __syncthreads();
  for (int off = 64; off > 0; off >>= 1) {
    if (j < off) hs[j] += hs[j + off];
    __syncthreads();
  }
  if (j == 0) out[g] = hs[0] + bp2[0];
}

extern "C" void kernel_launch(void* const* d_in, const int* in_sizes, int n_in,
                              void* d_out, int out_size, void* d_ws, size_t ws_size,
                              hipStream_t stream) {
  const float* x    = (const float*)d_in[0];
  const int*   eidx = (const int*)d_in[1];
  const int*   batch= (const int*)d_in[2];
  const float* W0 = (const float*)d_in[3];
  const float* b0 = (const float*)d_in[4];
  const float* W1 = (const float*)d_in[5];
  const float* b1 = (const float*)d_in[6];
  const float* W2 = (const float*)d_in[7];
  const float* b2 = (const float*)d_in[8];
  const float* Wp1 = (const float*)d_in[9];
  const float* bp1 = (const float*)d_in[10];
  const float* Wp2 = (const float*)d_in[11];
  const float* bp2 = (const float*)d_in[12];
  float* out = (float*)d_out;

  const int N = in_sizes[0] / 128;
  const int E = in_sizes[1] / 2;
  const int G = out_size;
  const int M = E + N;
  const int T = (N + 1023) / 1024;  // #scan tiles; N<=131072 keeps T<=128

  const int* src = eidx;
  const int* dst = eidx + E;

  char* ws = (char*)d_ws;
  size_t off = 0;
  auto alloc = [&](size_t bytes) -> void* {
    void* p = ws + off;
    off = (off + bytes + 255) & ~(size_t)255;
    return p;
  };
  int*   indeg   = (int*)  alloc((size_t)N * 4);
  int*   ptr     = (int*)  alloc((size_t)(N + 1) * 4);
  int*   cursor  = (int*)  alloc((size_t)N * 4);
  int2*  emeta   = (int2*) alloc((size_t)M * 8);
  float* bufH    = (float*)alloc((size_t)N * 128 * 4);
  float* bufX    = (float*)alloc((size_t)N * 128 * 4);
  int*   gptr    = (int*)  alloc((size_t)(G + 1) * 4);
  int*   tilesum = (int*)  alloc((size_t)T * 4);
  int*   tileoff = (int*)  alloc((size_t)T * 4);
  short* whi[3], *wlo[3];
  for (int l = 0; l < 3; ++l) {
    whi[l] = (short*)alloc(16384 * 2);
    wlo[l] = (short*)alloc(16384 * 2);
  }
  (void)ws_size;

  hipMemsetAsync(indeg,  0, (size_t)N * 4, stream);
  hipMemsetAsync(cursor, 0, (size_t)N * 4, stream);

  count_deg_kernel<<<(E + 255) / 256, 256, 0, stream>>>(dst, indeg, E);
  tile_reduce_kernel<<<T, 1024, 0, stream>>>(indeg, tilesum, N);
  scan_tiles_kernel<<<1, 128, 0, stream>>>(tilesum, tileoff, ptr + N, T);
  scan_emit_kernel<<<T, 1024, 0, stream>>>(indeg, tileoff, ptr, N);
  fill_all_kernel<<<(E + N + 255) / 256, 256, 0, stream>>>(src, dst, indeg, ptr, cursor, emeta, E, N);
  graph_bounds_kernel<<<(N + 255) / 256, 256, 0, stream>>>(batch, gptr, N, G);
  wsplit_kernel<<<64, 256, 0, stream>>>(W0, whi[0], wlo[0]);
  wsplit_kernel<<<64, 256, 0, stream>>>(W1, whi[1], wlo[1]);
  wsplit_kernel<<<64, 256, 0, stream>>>(W2, whi[2], wlo[2]);

  dim3 gemm_grid((N + 63) / 64);
  dim3 agg_grid((N + 7) / 8);

  gemm_mfma_kernel<<<gemm_grid, 256, 0, stream>>>(x,    whi[0], wlo[0], b0, bufH, N);
  aggregate_kernel<<<agg_grid, 256, 0, stream>>>(bufH, ptr, emeta, bufX, N);
  gemm_mfma_kernel<<<gemm_grid, 256, 0, stream>>>(bufX, whi[1], wlo[1], b1, bufH, N);
  aggregate_kernel<<<agg_grid, 256, 0, stream>>>(bufH, ptr, emeta, bufX, N);
  gemm_mfma_kernel<<<gemm_grid, 256, 0, stream>>>(bufX, whi[2], wlo[2], b2, bufH, N);
  aggregate_kernel<<<agg_grid, 256, 0, stream>>>(bufH, ptr, emeta, bufX, N);

  pool_head_kernel<<<G, 128, 0, stream>>>(bufX, gptr, Wp1, bp1, Wp2, bp2, out, G);
}

// Round 8
// 688.057 us; speedup vs baseline: 1.5311x; 1.0654x over previous
//
#include <hip/hip_runtime.h>
#include <hip/hip_bf16.h>
#include <math.h>

// ---------------------------------------------------------------------------
// GCN GraphRegressor: 3x (linear -> gather*norm -> scatter-sum -> relu)
//                     -> segment-mean pool -> MLP head
// R8: layers 2,3 run as FUSED aggregate+GEMM: half-waves gather 16 node rows,
//     pack relu'd bf16 hi/lo into LDS, block MFMAs the 16x128 tile vs the
//     pre-split W (3-term bf16 split). Kills bufX write+read (204 MB).
//     Single wsplit launch; merged memsets. Aggregate core = R5 flat form.
// Floors (measured): aggregate FETCH 402MB = 100K rows x 512B x 8 XCD
// compulsory per-XCD fill; ~119us/aggregate at ~3.9 TB/s.
// ---------------------------------------------------------------------------

typedef float f32x4 __attribute__((ext_vector_type(4)));
typedef short s16x8 __attribute__((ext_vector_type(8)));

__device__ __forceinline__ unsigned short f2bf(float x) {
  unsigned u = __float_as_uint(x);
  unsigned r = (u + 0x7FFFu + ((u >> 16) & 1u)) >> 16;
  return (unsigned short)r;
}

__global__ void count_deg_kernel(const int* __restrict__ dst, int* __restrict__ indeg, int E) {
  int e = blockIdx.x * 256 + threadIdx.x;
  if (e < E) atomicAdd(&indeg[dst[e]], 1);
}

// ---- 3-phase exclusive scan of (indeg[i]+1) into ptr[0..n] ----------------
__global__ __launch_bounds__(1024) void tile_reduce_kernel(
    const int* __restrict__ indeg, int* __restrict__ tilesum, int n) {
  __shared__ int ws[16];
  int i = blockIdx.x * 1024 + threadIdx.x;
  int v = (i < n) ? (indeg[i] + 1) : 0;
  for (int off = 32; off > 0; off >>= 1) v += __shfl_down(v, off);
  int wid = threadIdx.x >> 6, lane = threadIdx.x & 63;
  if (lane == 0) ws[wid] = v;
  __syncthreads();
  if (threadIdx.x == 0) {
    int s = 0;
    for (int w = 0; w < 16; ++w) s += ws[w];
    tilesum[blockIdx.x] = s;
  }
}

__global__ __launch_bounds__(128) void scan_tiles_kernel(
    const int* __restrict__ tilesum, int* __restrict__ tileoff,
    int* __restrict__ ptr_last, int T) {
  __shared__ int sm[128];
  int v = (threadIdx.x < T) ? tilesum[threadIdx.x] : 0;
  sm[threadIdx.x] = v;
  __syncthreads();
  for (int off = 1; off < 128; off <<= 1) {
    int t = (threadIdx.x >= off) ? sm[threadIdx.x - off] : 0;
    __syncthreads();
    sm[threadIdx.x] += t;
    __syncthreads();
  }
  if (threadIdx.x < T) tileoff[threadIdx.x] = sm[threadIdx.x] - v;
  if (threadIdx.x == 127) *ptr_last = sm[127];
}

__global__ __launch_bounds__(1024) void scan_emit_kernel(
    const int* __restrict__ indeg, const int* __restrict__ tileoff,
    int* __restrict__ ptr, int n) {
  __shared__ int wsum[16];
  int i = blockIdx.x * 1024 + threadIdx.x;
  int v = (i < n) ? (indeg[i] + 1) : 0;
  int lane = threadIdx.x & 63, wid = threadIdx.x >> 6;
  int x = v;
  for (int off = 1; off < 64; off <<= 1) {
    int y = __shfl_up(x, off);
    if (lane >= off) x += y;
  }
  if (lane == 63) wsum[wid] = x;
  __syncthreads();
  if (threadIdx.x == 0) {
    int run = 0;
    for (int w = 0; w < 16; ++w) { int t = wsum[w]; wsum[w] = run; run += t; }
  }
  __syncthreads();
  if (i < n) ptr[i] = x - v + wsum[wid] + tileoff[blockIdx.x];
}

// merged edge + self-loop CSR fill
__global__ void fill_all_kernel(const int* __restrict__ src, const int* __restrict__ dst,
                                const int* __restrict__ indeg, const int* __restrict__ ptr,
                                int* __restrict__ cursor, int2* __restrict__ emeta,
                                int E, int n) {
  int i = blockIdx.x * 256 + threadIdx.x;
  if (i < E) {
    int s = src[i], d = dst[i];
    int pos = ptr[d] + atomicAdd(&cursor[d], 1);
    float dd = (float)(indeg[s] + 1) * (float)(indeg[d] + 1);
    emeta[pos] = make_int2(s, __float_as_int(1.0f / sqrtf(dd)));
  } else if (i < E + n) {
    int v = i - E;
    int pos = ptr[v] + atomicAdd(&cursor[v], 1);
    emeta[pos] = make_int2(v, __float_as_int(1.0f / (float)(indeg[v] + 1)));
  }
}

// graph boundaries from sorted batch: gptr[g] = first node with batch >= g
__global__ void graph_bounds_kernel(const int* __restrict__ batch,
                                    int* __restrict__ gptr, int n, int G) {
  int i = blockIdx.x * 256 + threadIdx.x;
  if (i >= n) return;
  int b = batch[i];
  if (i == 0) {
    for (int g = 0; g <= b; ++g) gptr[g] = 0;
  } else {
    int bp = batch[i - 1];
    for (int g = bp + 1; g <= b; ++g) gptr[g] = i;
  }
  if (i == n - 1) {
    for (int g = b + 1; g <= G; ++g) gptr[g] = n;
  }
}

// Split all three W[128x128] into bf16 hi/lo MFMA B-fragment layout.
// frag index i = ((ntile*4 + kstep)*64 + lane)*8 + j ;
// k = kstep*32 + (lane>>4)*8 + j ; n = ntile*16 + (lane&15)
__global__ __launch_bounds__(256) void wsplit3_kernel(
    const float* __restrict__ W0, const float* __restrict__ W1,
    const float* __restrict__ W2, short* __restrict__ Whi, short* __restrict__ Wlo) {
  int layer = blockIdx.x >> 6;
  int i = (blockIdx.x & 63) * 256 + threadIdx.x;
  const float* W = (layer == 0) ? W0 : (layer == 1) ? W1 : W2;
  int j = i & 7, lane = (i >> 3) & 63, ks = (i >> 9) & 3, nt = i >> 11;
  int k = ks * 32 + (lane >> 4) * 8 + j;
  int nn = nt * 16 + (lane & 15);
  float w = W[k * 128 + nn];
  unsigned short h = f2bf(w);
  float hf = __uint_as_float(((unsigned)h) << 16);
  Whi[layer * 16384 + i] = (short)h;
  Wlo[layer * 16384 + i] = (short)f2bf(w - hf);
}

// H[n,128] = X[n,128] @ W + bias via 3x bf16-split MFMA (layer-1 only).
__global__ __launch_bounds__(256) void gemm_mfma_kernel(
    const float* __restrict__ X, const short* __restrict__ Whi,
    const short* __restrict__ Wlo, const float* __restrict__ bias,
    float* __restrict__ H, int n) {
  int wave = threadIdx.x >> 6, lane = threadIdx.x & 63;
  int quad = lane >> 4, m = lane & 15;
  int mbase = blockIdx.x * 64 + wave * 16;
  int row = min(mbase + m, n - 1);
  const float* xr = X + (size_t)row * 128 + quad * 8;
  const s16x8* WH = (const s16x8*)Whi;
  const s16x8* WL = (const s16x8*)Wlo;

  f32x4 acc[8];
#pragma unroll
  for (int nt = 0; nt < 8; ++nt) acc[nt] = 0.f;

#pragma unroll
  for (int ks = 0; ks < 4; ++ks) {
    float4 xa = *(const float4*)(xr + ks * 32);
    float4 xb = *(const float4*)(xr + ks * 32 + 4);
    float xs[8] = {xa.x, xa.y, xa.z, xa.w, xb.x, xb.y, xb.z, xb.w};
    s16x8 ah, al;
#pragma unroll
    for (int j = 0; j < 8; ++j) {
      unsigned short h = f2bf(xs[j]);
      float hf = __uint_as_float(((unsigned)h) << 16);
      ah[j] = (short)h;
      al[j] = (short)f2bf(xs[j] - hf);
    }
#pragma unroll
    for (int nt = 0; nt < 8; ++nt) {
      s16x8 wh = WH[(nt * 4 + ks) * 64 + lane];
      s16x8 wl = WL[(nt * 4 + ks) * 64 + lane];
      acc[nt] = __builtin_amdgcn_mfma_f32_16x16x32_bf16(ah, wh, acc[nt], 0, 0, 0);
      acc[nt] = __builtin_amdgcn_mfma_f32_16x16x32_bf16(al, wh, acc[nt], 0, 0, 0);
      acc[nt] = __builtin_amdgcn_mfma_f32_16x16x32_bf16(ah, wl, acc[nt], 0, 0, 0);
    }
  }

#pragma unroll
  for (int nt = 0; nt < 8; ++nt) {
    int col = nt * 16 + m;
    float b = bias[col];
#pragma unroll
    for (int r = 0; r < 4; ++r) {
      int rr = mbase + quad * 4 + r;
      if (rr < n) H[(size_t)rr * 128 + col] = acc[nt][r] + b;
    }
  }
}

// R5 aggregate core: half-wave gathers one node row; guarded 8-deep unroll.
__device__ __forceinline__ f32x4 agg_node(
    const f32x4* __restrict__ Hc, const int* __restrict__ ptr,
    const int2* __restrict__ emeta, int node, int hl) {
  int beg = ptr[node], end = ptr[node + 1];
  f32x4 a0 = 0.f, a1 = 0.f, a2 = 0.f, a3 = 0.f;
  f32x4 a4 = 0.f, a5 = 0.f, a6 = 0.f, a7 = 0.f;
  for (int base = beg; base < end; base += 32) {
    int m = end - base;
    if (m > 32) m = 32;
    int idx = base + hl;
    int2 mv = (hl < m) ? emeta[idx] : make_int2(0, 0);
    int sl = mv.x;
    float nl = __int_as_float(mv.y);
    int j = 0;
    for (; j + 7 < m; j += 8) {
      int s0 = __shfl(sl, j + 0, 32), s1 = __shfl(sl, j + 1, 32);
      int s2 = __shfl(sl, j + 2, 32), s3 = __shfl(sl, j + 3, 32);
      int s4 = __shfl(sl, j + 4, 32), s5 = __shfl(sl, j + 5, 32);
      int s6 = __shfl(sl, j + 6, 32), s7 = __shfl(sl, j + 7, 32);
      float n0 = __shfl(nl, j + 0, 32), n1 = __shfl(nl, j + 1, 32);
      float n2 = __shfl(nl, j + 2, 32), n3 = __shfl(nl, j + 3, 32);
      float n4 = __shfl(nl, j + 4, 32), n5 = __shfl(nl, j + 5, 32);
      float n6 = __shfl(nl, j + 6, 32), n7 = __shfl(nl, j + 7, 32);
      f32x4 h0 = Hc[(size_t)s0 * 32];
      f32x4 h1 = Hc[(size_t)s1 * 32];
      f32x4 h2 = Hc[(size_t)s2 * 32];
      f32x4 h3 = Hc[(size_t)s3 * 32];
      f32x4 h4 = Hc[(size_t)s4 * 32];
      f32x4 h5 = Hc[(size_t)s5 * 32];
      f32x4 h6 = Hc[(size_t)s6 * 32];
      f32x4 h7 = Hc[(size_t)s7 * 32];
      a0 += h0 * n0; a1 += h1 * n1; a2 += h2 * n2; a3 += h3 * n3;
      a4 += h4 * n4; a5 += h5 * n5; a6 += h6 * n6; a7 += h7 * n7;
    }
    for (; j + 3 < m; j += 4) {
      int s0 = __shfl(sl, j + 0, 32), s1 = __shfl(sl, j + 1, 32);
      int s2 = __shfl(sl, j + 2, 32), s3 = __shfl(sl, j + 3, 32);
      float n0 = __shfl(nl, j + 0, 32), n1 = __shfl(nl, j + 1, 32);
      float n2 = __shfl(nl, j + 2, 32), n3 = __shfl(nl, j + 3, 32);
      f32x4 h0 = Hc[(size_t)s0 * 32];
      f32x4 h1 = Hc[(size_t)s1 * 32];
      f32x4 h2 = Hc[(size_t)s2 * 32];
      f32x4 h3 = Hc[(size_t)s3 * 32];
      a0 += h0 * n0; a1 += h1 * n1; a2 += h2 * n2; a3 += h3 * n3;
    }
    for (; j < m; ++j) {
      int s0 = __shfl(sl, j, 32);
      float n0 = __shfl(nl, j, 32);
      f32x4 h0 = Hc[(size_t)s0 * 32];
      a0 += h0 * n0;
    }
  }
  f32x4 s = ((a0 + a1) + (a2 + a3)) + ((a4 + a5) + (a6 + a7));
  f32x4 o;
  o.x = fmaxf(s.x, 0.f);
  o.y = fmaxf(s.y, 0.f);
  o.z = fmaxf(s.z, 0.f);
  o.w = fmaxf(s.w, 0.f);
  return o;
}

// Standalone aggregate (layer 3): writes relu'd rows to Xout.
__global__ __launch_bounds__(256) void aggregate_kernel(
    const float* __restrict__ H, const int* __restrict__ ptr,
    const int2* __restrict__ emeta, float* __restrict__ Xout, int n) {
  int node = blockIdx.x * 8 + (threadIdx.x >> 5);
  if (node >= n) return;
  int hl = threadIdx.x & 31;
  const f32x4* Hc = (const f32x4*)(H + hl * 4);
  f32x4 o = agg_node(Hc, ptr, emeta, node, hl);
  *(f32x4*)(Xout + (size_t)node * 128 + hl * 4) = o;
}

// FUSED aggregate + next-layer GEMM: block handles 16 nodes.
// Phase 1: 8 half-waves aggregate 2 nodes each, pack relu'd bf16 hi/lo
// into LDS (row stride 132 ints -> 2-way bank aliasing only, free).
// Phase 2: 4 waves MFMA the 16x128 tile vs pre-split W; write Hout+bias.
#define LDS_STRIDE 132
__global__ __launch_bounds__(256) void agg_gemm_kernel(
    const float* __restrict__ H, const int* __restrict__ ptr,
    const int2* __restrict__ emeta, const short* __restrict__ Whi,
    const short* __restrict__ Wlo, const float* __restrict__ bias,
    float* __restrict__ Hout, int n) {
  __shared__ int lds[16 * LDS_STRIDE];
  int hw = threadIdx.x >> 5, hl = threadIdx.x & 31;
  int nbase = blockIdx.x * 16;
  const f32x4* Hc = (const f32x4*)(H + hl * 4);
#pragma unroll
  for (int rep = 0; rep < 2; ++rep) {
    int nl = hw + rep * 8;
    int node = nbase + nl;
    f32x4 o = (node < n) ? agg_node(Hc, ptr, emeta, node, hl)
                         : (f32x4)0.f;
    int* dst = lds + nl * LDS_STRIDE + hl * 4;
#pragma unroll
    for (int c = 0; c < 4; ++c) {
      float v = o[c];
      unsigned short h = f2bf(v);
      float hf = __uint_as_float(((unsigned)h) << 16);
      unsigned short l = f2bf(v - hf);
      dst[c] = (int)((((unsigned)h) << 16) | l);
    }
  }
  __syncthreads();

  int wave = threadIdx.x >> 6, lane = threadIdx.x & 63;
  int quad = lane >> 4, m = lane & 15;
  const s16x8* WH = (const s16x8*)Whi;
  const s16x8* WL = (const s16x8*)Wlo;
  f32x4 acc0 = 0.f, acc1 = 0.f;
  int nt0 = wave * 2, nt1 = wave * 2 + 1;
#pragma unroll
  for (int ks = 0; ks < 4; ++ks) {
    const int* arow = lds + m * LDS_STRIDE + ks * 32 + quad * 8;
    s16x8 ah, al;
#pragma unroll
    for (int j = 0; j < 8; ++j) {
      unsigned p = (unsigned)arow[j];
      ah[j] = (short)(p >> 16);
      al[j] = (short)(p & 0xffffu);
    }
    s16x8 wh0 = WH[(nt0 * 4 + ks) * 64 + lane];
    s16x8 wl0 = WL[(nt0 * 4 + ks) * 64 + lane];
    s16x8 wh1 = WH[(nt1 * 4 + ks) * 64 + lane];
    s16x8 wl1 = WL[(nt1 * 4 + ks) * 64 + lane];
    acc0 = __builtin_amdgcn_mfma_f32_16x16x32_bf16(ah, wh0, acc0, 0, 0, 0);
    acc0 = __builtin_amdgcn_mfma_f32_16x16x32_bf16(al, wh0, acc0, 0, 0, 0);
    acc0 = __builtin_amdgcn_mfma_f32_16x16x32_bf16(ah, wl0, acc0, 0, 0, 0);
    acc1 = __builtin_amdgcn_mfma_f32_16x16x32_bf16(ah, wh1, acc1, 0, 0, 0);
    acc1 = __builtin_amdgcn_mfma_f32_16x16x32_bf16(al, wh1, acc1, 0, 0, 0);
    acc1 = __builtin_amdgcn_mfma_f32_16x16x32_bf16(ah, wl1, acc1, 0, 0, 0);
  }
#pragma unroll
  for (int t = 0; t < 2; ++t) {
    int nt = wave * 2 + t;
    int col = nt * 16 + m;
    float b = bias[col];
    f32x4 a = t ? acc1 : acc0;
#pragma unroll
    for (int r = 0; r < 4; ++r) {
      int rr = nbase + quad * 4 + r;
      if (rr < n) Hout[(size_t)rr * 128 + col] = a[r] + b;
    }
  }
}

// Pool (segment-mean over sorted batch, atomic-free) + MLP head, fused.
__global__ __launch_bounds__(128) void pool_head_kernel(
    const float* __restrict__ X, const int* __restrict__ gptr,
    const float* __restrict__ Wp1, const float* __restrict__ bp1,
    const float* __restrict__ Wp2, const float* __restrict__ bp2,
    float* __restrict__ out, int G) {
  int g = blockIdx.x;
  int j = threadIdx.x;
  int beg = gptr[g], end = gptr[g + 1];
  __shared__ float ps[128];
  __shared__ float hs[128];
  float s0 = 0.f, s1 = 0.f, s2 = 0.f, s3 = 0.f;
  int i = beg;
  for (; i + 3 < end; i += 4) {
    s0 += X[(size_t)i * 128 + j];
    s1 += X[(size_t)(i + 1) * 128 + j];
    s2 += X[(size_t)(i + 2) * 128 + j];
    s3 += X[(size_t)(i + 3) * 128 + j];
  }
  for (; i < end; ++i) s0 += X[(size_t)i * 128 + j];
  float inv = 1.0f / (float)max(end - beg, 1);
  ps[j] = ((s0 + s1) + (s2 + s3)) * inv;
  __syncthreads();
  float acc = bp1[j];
#pragma unroll 8
  for (int k = 0; k < 128; ++k) acc = fmaf(ps[k], Wp1[k * 128 + j], acc);
  hs[j] = fmaxf(acc, 0.f) * Wp2[j];
  __syncthreads();
  for (int off = 64; off > 0; off >>= 1) {
    if (j < off) hs[j] += hs[j + off];
    __syncthreads();
  }
  if (j == 0) out[g] = hs[0] + bp2[0];
}

extern "C" void kernel_launch(void* const* d_in, const int* in_sizes, int n_in,
                              void* d_out, int out_size, void* d_ws, size_t ws_size,
                              hipStream_t stream) {
  const float* x    = (const float*)d_in[0];
  const int*   eidx = (const int*)d_in[1];
  const int*   batch= (const int*)d_in[2];
  const float* W0 = (const float*)d_in[3];
  const float* b0 = (const float*)d_in[4];
  const float* W1 = (const float*)d_in[5];
  const float* b1 = (const float*)d_in[6];
  const float* W2 = (const float*)d_in[7];
  const float* b2 = (const float*)d_in[8];
  const float* Wp1 = (const float*)d_in[9];
  const float* bp1 = (const float*)d_in[10];
  const float* Wp2 = (const float*)d_in[11];
  const float* bp2 = (const float*)d_in[12];
  float* out = (float*)d_out;

  const int N = in_sizes[0] / 128;
  const int E = in_sizes[1] / 2;
  const int G = out_size;
  const int M = E + N;
  const int T = (N + 1023) / 1024;  // #scan tiles; N<=131072 keeps T<=128

  const int* src = eidx;
  const int* dst = eidx + E;

  char* ws = (char*)d_ws;
  size_t off = 0;
  auto alloc = [&](size_t bytes) -> void* {
    void* p = ws + off;
    off = (off + bytes + 255) & ~(size_t)255;
    return p;
  };
  int*   indeg   = (int*)  alloc((size_t)N * 4);
  int*   cursor  = (int*)  alloc((size_t)N * 4);   // adjacent to indeg: 1 memset
  int*   ptr     = (int*)  alloc((size_t)(N + 1) * 4);
  int2*  emeta   = (int2*) alloc((size_t)M * 8);
  float* bufA    = (float*)alloc((size_t)N * 128 * 4);
  float* bufB    = (float*)alloc((size_t)N * 128 * 4);
  int*   gptr    = (int*)  alloc((size_t)(G + 1) * 4);
  int*   tilesum = (int*)  alloc((size_t)T * 4);
  int*   tileoff = (int*)  alloc((size_t)T * 4);
  short* whi     = (short*)alloc(3 * 16384 * 2);
  short* wlo     = (short*)alloc(3 * 16384 * 2);
  (void)ws_size;

  // indeg+cursor are contiguous (alloc rounds 400000B to 256-multiple; the
  // pad bytes between them are also cleared — harmless)
  hipMemsetAsync(indeg, 0, (size_t)((char*)ptr - (char*)indeg), stream);

  count_deg_kernel<<<(E + 255) / 256, 256, 0, stream>>>(dst, indeg, E);
  tile_reduce_kernel<<<T, 1024, 0, stream>>>(indeg, tilesum, N);
  scan_tiles_kernel<<<1, 128, 0, stream>>>(tilesum, tileoff, ptr + N, T);
  scan_emit_kernel<<<T, 1024, 0, stream>>>(indeg, tileoff, ptr, N);
  fill_all_kernel<<<(E + N + 255) / 256, 256, 0, stream>>>(src, dst, indeg, ptr, cursor, emeta, E, N);
  graph_bounds_kernel<<<(N + 255) / 256, 256, 0, stream>>>(batch, gptr, N, G);
  wsplit3_kernel<<<192, 256, 0, stream>>>(W0, W1, W2, whi, wlo);

  dim3 gemm_grid((N + 63) / 64);
  dim3 agg_grid((N + 7) / 8);
  dim3 fused_grid((N + 15) / 16);

  // L1: gemm1 -> bufA ; fused agg1+gemm2: bufA -> bufB ;
  // fused agg2+gemm3: bufB -> bufA ; agg3: bufA -> bufB ; pool(bufB)
  gemm_mfma_kernel<<<gemm_grid, 256, 0, stream>>>(x, whi, wlo, b0, bufA, N);
  agg_gemm_kernel<<<fused_grid, 256, 0, stream>>>(bufA, ptr, emeta,
      whi + 16384, wlo + 16384, b1, bufB, N);
  agg_gemm_kernel<<<fused_grid, 256, 0, stream>>>(bufB, ptr, emeta,
      whi + 2 * 16384, wlo + 2 * 16384, b2, bufA, N);
  aggregate_kernel<<<agg_grid, 256, 0, stream>>>(bufA, ptr, emeta, bufB, N);

  pool_head_kernel<<<G, 128, 0, stream>>>(bufB, gptr, Wp1, bp1, Wp2, bp2, out, G);
}

// Round 9
// 674.336 us; speedup vs baseline: 1.5622x; 1.0203x over previous
//
#include <hip/hip_runtime.h>
#include <hip/hip_bf16.h>
#include <math.h>

// ---------------------------------------------------------------------------
// GCN GraphRegressor: 3x (linear -> gather*norm -> scatter-sum -> relu)
//                     -> segment-mean pool -> MLP head
// R9: agg3 fused with pool (block-level per-graph partials -> sparse atomics);
//     CSR fill uses cursor pre-init to ptr (no random ptr reads, no memset);
//     scan_tiles folded into scan_emit; gemm1+count_deg+graph_bounds+poolzero
//     merged into one block-range uber-kernel (independent work overlapped).
// Floors (measured): gather kernels saturate ~3.9 TB/s random-512B fabric BW;
// FETCH 402MB = 100K rows x 512B x 8 XCD compulsory per-XCD fill.
// ---------------------------------------------------------------------------

typedef float f32x4 __attribute__((ext_vector_type(4)));
typedef short s16x8 __attribute__((ext_vector_type(8)));

__device__ __forceinline__ unsigned short f2bf(float x) {
  unsigned u = __float_as_uint(x);
  unsigned r = (u + 0x7FFFu + ((u >> 16) & 1u)) >> 16;
  return (unsigned short)r;
}

// ---- per-tile (1024) sums of indeg+1 --------------------------------------
__global__ __launch_bounds__(1024) void tile_reduce_kernel(
    const int* __restrict__ indeg, int* __restrict__ tilesum, int n) {
  __shared__ int ws[16];
  int i = blockIdx.x * 1024 + threadIdx.x;
  int v = (i < n) ? (indeg[i] + 1) : 0;
  for (int off = 32; off > 0; off >>= 1) v += __shfl_down(v, off);
  int wid = threadIdx.x >> 6, lane = threadIdx.x & 63;
  if (lane == 0) ws[wid] = v;
  __syncthreads();
  if (threadIdx.x == 0) {
    int s = 0;
    for (int w = 0; w < 16; ++w) s += ws[w];
    tilesum[blockIdx.x] = s;
  }
}

// ---- per-tile scan + own tile-prefix; writes ptr AND cursor(=ptr) ---------
__global__ __launch_bounds__(1024) void scan_emit_kernel(
    const int* __restrict__ indeg, const int* __restrict__ tilesum,
    int* __restrict__ ptr, int* __restrict__ cursor, int n, int T) {
  __shared__ int wsum[16];
  __shared__ int tilebase_s;
  int bid = blockIdx.x;
  int lane = threadIdx.x & 63, wid = threadIdx.x >> 6;
  if (threadIdx.x < 64) {
    int acc = 0;
    for (int t = threadIdx.x; t < bid; t += 64) acc += tilesum[t];
    for (int off = 32; off > 0; off >>= 1) acc += __shfl_down(acc, off);
    if (threadIdx.x == 0) tilebase_s = acc;
  }
  __syncthreads();
  int tilebase = tilebase_s;
  int i = bid * 1024 + threadIdx.x;
  int v = (i < n) ? (indeg[i] + 1) : 0;
  int x = v;
  for (int off = 1; off < 64; off <<= 1) {
    int y = __shfl_up(x, off);
    if (lane >= off) x += y;
  }
  if (lane == 63) wsum[wid] = x;
  __syncthreads();
  if (threadIdx.x == 0) {
    int run = 0;
    for (int w = 0; w < 16; ++w) { int t = wsum[w]; wsum[w] = run; run += t; }
  }
  __syncthreads();
  if (i < n) {
    int p = x - v + wsum[wid] + tilebase;
    ptr[i] = p;
    cursor[i] = p;
  }
  if (bid == T - 1 && threadIdx.x == 1023) ptr[n] = tilebase + wsum[15] + x;
}

// merged edge + self-loop CSR fill; cursor pre-initialized to ptr
__global__ void fill_all_kernel(const int* __restrict__ src, const int* __restrict__ dst,
                                const int* __restrict__ indeg, int* __restrict__ cursor,
                                int2* __restrict__ emeta, int E, int n) {
  int i = blockIdx.x * 256 + threadIdx.x;
  if (i < E) {
    int s = src[i], d = dst[i];
    int pos = atomicAdd(&cursor[d], 1);
    float dd = (float)(indeg[s] + 1) * (float)(indeg[d] + 1);
    emeta[pos] = make_int2(s, __float_as_int(1.0f / sqrtf(dd)));
  } else if (i < E + n) {
    int v = i - E;
    int pos = atomicAdd(&cursor[v], 1);
    emeta[pos] = make_int2(v, __float_as_int(1.0f / (float)(indeg[v] + 1)));
  }
}

// Split all three W[128x128] into bf16 hi/lo MFMA B-fragment layout.
__global__ __launch_bounds__(256) void wsplit3_kernel(
    const float* __restrict__ W0, const float* __restrict__ W1,
    const float* __restrict__ W2, short* __restrict__ Whi, short* __restrict__ Wlo) {
  int layer = blockIdx.x >> 6;
  int i = (blockIdx.x & 63) * 256 + threadIdx.x;
  const float* W = (layer == 0) ? W0 : (layer == 1) ? W1 : W2;
  int j = i & 7, lane = (i >> 3) & 63, ks = (i >> 9) & 3, nt = i >> 11;
  int k = ks * 32 + (lane >> 4) * 8 + j;
  int nn = nt * 16 + (lane & 15);
  float w = W[k * 128 + nn];
  unsigned short h = f2bf(w);
  float hf = __uint_as_float(((unsigned)h) << 16);
  Whi[layer * 16384 + i] = (short)h;
  Wlo[layer * 16384 + i] = (short)f2bf(w - hf);
}

// gemm1 body: H[n,128] = X @ W + b via 3x bf16-split MFMA (one 64-row block)
__device__ __forceinline__ void gemm1_body(
    int blk, const float* __restrict__ X, const short* __restrict__ Whi,
    const short* __restrict__ Wlo, const float* __restrict__ bias,
    float* __restrict__ H, int n) {
  int wave = threadIdx.x >> 6, lane = threadIdx.x & 63;
  int quad = lane >> 4, m = lane & 15;
  int mbase = blk * 64 + wave * 16;
  int row = min(mbase + m, n - 1);
  const float* xr = X + (size_t)row * 128 + quad * 8;
  const s16x8* WH = (const s16x8*)Whi;
  const s16x8* WL = (const s16x8*)Wlo;
  f32x4 acc[8];
#pragma unroll
  for (int nt = 0; nt < 8; ++nt) acc[nt] = 0.f;
#pragma unroll
  for (int ks = 0; ks < 4; ++ks) {
    float4 xa = *(const float4*)(xr + ks * 32);
    float4 xb = *(const float4*)(xr + ks * 32 + 4);
    float xs[8] = {xa.x, xa.y, xa.z, xa.w, xb.x, xb.y, xb.z, xb.w};
    s16x8 ah, al;
#pragma unroll
    for (int j = 0; j < 8; ++j) {
      unsigned short h = f2bf(xs[j]);
      float hf = __uint_as_float(((unsigned)h) << 16);
      ah[j] = (short)h;
      al[j] = (short)f2bf(xs[j] - hf);
    }
#pragma unroll
    for (int nt = 0; nt < 8; ++nt) {
      s16x8 wh = WH[(nt * 4 + ks) * 64 + lane];
      s16x8 wl = WL[(nt * 4 + ks) * 64 + lane];
      acc[nt] = __builtin_amdgcn_mfma_f32_16x16x32_bf16(ah, wh, acc[nt], 0, 0, 0);
      acc[nt] = __builtin_amdgcn_mfma_f32_16x16x32_bf16(al, wh, acc[nt], 0, 0, 0);
      acc[nt] = __builtin_amdgcn_mfma_f32_16x16x32_bf16(ah, wl, acc[nt], 0, 0, 0);
    }
  }
#pragma unroll
  for (int nt = 0; nt < 8; ++nt) {
    int col = nt * 16 + m;
    float b = bias[col];
#pragma unroll
    for (int r = 0; r < 4; ++r) {
      int rr = mbase + quad * 4 + r;
      if (rr < n) H[(size_t)rr * 128 + col] = acc[nt][r] + b;
    }
  }
}

// uber-kernel: [gemm1 | count_deg | graph_bounds | pool-zero] by block range
__global__ __launch_bounds__(256) void uberA_kernel(
    const float* __restrict__ x, const short* __restrict__ Whi,
    const short* __restrict__ Wlo, const float* __restrict__ b0,
    float* __restrict__ bufA, int n,
    const int* __restrict__ dst, int* __restrict__ indeg, int E,
    const int* __restrict__ batch, int* __restrict__ gptr, int G,
    float* __restrict__ pool, int GB, int CD, int GBD, int PZ) {
  int b = blockIdx.x;
  if (b < GB) {
    gemm1_body(b, x, Whi, Wlo, b0, bufA, n);
  } else if (b < GB + CD) {
    int e = (b - GB) * 256 + threadIdx.x;
    if (e < E) atomicAdd(&indeg[dst[e]], 1);
  } else if (b < GB + CD + GBD) {
    int i = (b - GB - CD) * 256 + threadIdx.x;
    if (i < n) {
      int bb = batch[i];
      if (i == 0) {
        for (int g = 0; g <= bb; ++g) gptr[g] = 0;
      } else {
        int bp = batch[i - 1];
        for (int g = bp + 1; g <= bb; ++g) gptr[g] = i;
      }
      if (i == n - 1) {
        for (int g = bb + 1; g <= G; ++g) gptr[g] = n;
      }
    }
  } else {
    int i = (b - GB - CD - GBD) * 256 + threadIdx.x;
    if (i * 4 < G * 128) ((float4*)pool)[i] = make_float4(0.f, 0.f, 0.f, 0.f);
  }
}

// R5 aggregate core: half-wave gathers one node row; guarded 8-deep unroll.
__device__ __forceinline__ f32x4 agg_node(
    const f32x4* __restrict__ Hc, const int* __restrict__ ptr,
    const int2* __restrict__ emeta, int node, int hl) {
  int beg = ptr[node], end = ptr[node + 1];
  f32x4 a0 = 0.f, a1 = 0.f, a2 = 0.f, a3 = 0.f;
  f32x4 a4 = 0.f, a5 = 0.f, a6 = 0.f, a7 = 0.f;
  for (int base = beg; base < end; base += 32) {
    int m = end - base;
    if (m > 32) m = 32;
    int idx = base + hl;
    int2 mv = (hl < m) ? emeta[idx] : make_int2(0, 0);
    int sl = mv.x;
    float nl = __int_as_float(mv.y);
    int j = 0;
    for (; j + 7 < m; j += 8) {
      int s0 = __shfl(sl, j + 0, 32), s1 = __shfl(sl, j + 1, 32);
      int s2 = __shfl(sl, j + 2, 32), s3 = __shfl(sl, j + 3, 32);
      int s4 = __shfl(sl, j + 4, 32), s5 = __shfl(sl, j + 5, 32);
      int s6 = __shfl(sl, j + 6, 32), s7 = __shfl(sl, j + 7, 32);
      float n0 = __shfl(nl, j + 0, 32), n1 = __shfl(nl, j + 1, 32);
      float n2 = __shfl(nl, j + 2, 32), n3 = __shfl(nl, j + 3, 32);
      float n4 = __shfl(nl, j + 4, 32), n5 = __shfl(nl, j + 5, 32);
      float n6 = __shfl(nl, j + 6, 32), n7 = __shfl(nl, j + 7, 32);
      f32x4 h0 = Hc[(size_t)s0 * 32];
      f32x4 h1 = Hc[(size_t)s1 * 32];
      f32x4 h2 = Hc[(size_t)s2 * 32];
      f32x4 h3 = Hc[(size_t)s3 * 32];
      f32x4 h4 = Hc[(size_t)s4 * 32];
      f32x4 h5 = Hc[(size_t)s5 * 32];
      f32x4 h6 = Hc[(size_t)s6 * 32];
      f32x4 h7 = Hc[(size_t)s7 * 32];
      a0 += h0 * n0; a1 += h1 * n1; a2 += h2 * n2; a3 += h3 * n3;
      a4 += h4 * n4; a5 += h5 * n5; a6 += h6 * n6; a7 += h7 * n7;
    }
    for (; j + 3 < m; j += 4) {
      int s0 = __shfl(sl, j + 0, 32), s1 = __shfl(sl, j + 1, 32);
      int s2 = __shfl(sl, j + 2, 32), s3 = __shfl(sl, j + 3, 32);
      float n0 = __shfl(nl, j + 0, 32), n1 = __shfl(nl, j + 1, 32);
      float n2 = __shfl(nl, j + 2, 32), n3 = __shfl(nl, j + 3, 32);
      f32x4 h0 = Hc[(size_t)s0 * 32];
      f32x4 h1 = Hc[(size_t)s1 * 32];
      f32x4 h2 = Hc[(size_t)s2 * 32];
      f32x4 h3 = Hc[(size_t)s3 * 32];
      a0 += h0 * n0; a1 += h1 * n1; a2 += h2 * n2; a3 += h3 * n3;
    }
    for (; j < m; ++j) {
      int s0 = __shfl(sl, j, 32);
      float n0 = __shfl(nl, j, 32);
      f32x4 h0 = Hc[(size_t)s0 * 32];
      a0 += h0 * n0;
    }
  }
  f32x4 s = ((a0 + a1) + (a2 + a3)) + ((a4 + a5) + (a6 + a7));
  f32x4 o;
  o.x = fmaxf(s.x, 0.f);
  o.y = fmaxf(s.y, 0.f);
  o.z = fmaxf(s.z, 0.f);
  o.w = fmaxf(s.w, 0.f);
  return o;
}

// FUSED aggregate + next-layer GEMM (layers 2 and 3)
#define LDS_STRIDE 132
__global__ __launch_bounds__(256) void agg_gemm_kernel(
    const float* __restrict__ H, const int* __restrict__ ptr,
    const int2* __restrict__ emeta, const short* __restrict__ Whi,
    const short* __restrict__ Wlo, const float* __restrict__ bias,
    float* __restrict__ Hout, int n) {
  __shared__ int lds[16 * LDS_STRIDE];
  int hw = threadIdx.x >> 5, hl = threadIdx.x & 31;
  int nbase = blockIdx.x * 16;
  const f32x4* Hc = (const f32x4*)(H + hl * 4);
#pragma unroll
  for (int rep = 0; rep < 2; ++rep) {
    int nl = hw + rep * 8;
    int node = nbase + nl;
    f32x4 o = (node < n) ? agg_node(Hc, ptr, emeta, node, hl)
                         : (f32x4)0.f;
    int* dst = lds + nl * LDS_STRIDE + hl * 4;
#pragma unroll
    for (int c = 0; c < 4; ++c) {
      float v = o[c];
      unsigned short h = f2bf(v);
      float hf = __uint_as_float(((unsigned)h) << 16);
      unsigned short l = f2bf(v - hf);
      dst[c] = (int)((((unsigned)h) << 16) | l);
    }
  }
  __syncthreads();

  int wave = threadIdx.x >> 6, lane = threadIdx.x & 63;
  int quad = lane >> 4, m = lane & 15;
  const s16x8* WH = (const s16x8*)Whi;
  const s16x8* WL = (const s16x8*)Wlo;
  f32x4 acc0 = 0.f, acc1 = 0.f;
  int nt0 = wave * 2, nt1 = wave * 2 + 1;
#pragma unroll
  for (int ks = 0; ks < 4; ++ks) {
    const int* arow = lds + m * LDS_STRIDE + ks * 32 + quad * 8;
    s16x8 ah, al;
#pragma unroll
    for (int j = 0; j < 8; ++j) {
      unsigned p = (unsigned)arow[j];
      ah[j] = (short)(p >> 16);
      al[j] = (short)(p & 0xffffu);
    }
    s16x8 wh0 = WH[(nt0 * 4 + ks) * 64 + lane];
    s16x8 wl0 = WL[(nt0 * 4 + ks) * 64 + lane];
    s16x8 wh1 = WH[(nt1 * 4 + ks) * 64 + lane];
    s16x8 wl1 = WL[(nt1 * 4 + ks) * 64 + lane];
    acc0 = __builtin_amdgcn_mfma_f32_16x16x32_bf16(ah, wh0, acc0, 0, 0, 0);
    acc0 = __builtin_amdgcn_mfma_f32_16x16x32_bf16(al, wh0, acc0, 0, 0, 0);
    acc0 = __builtin_amdgcn_mfma_f32_16x16x32_bf16(ah, wl0, acc0, 0, 0, 0);
    acc1 = __builtin_amdgcn_mfma_f32_16x16x32_bf16(ah, wh1, acc1, 0, 0, 0);
    acc1 = __builtin_amdgcn_mfma_f32_16x16x32_bf16(al, wh1, acc1, 0, 0, 0);
    acc1 = __builtin_amdgcn_mfma_f32_16x16x32_bf16(ah, wl1, acc1, 0, 0, 0);
  }
#pragma unroll
  for (int t = 0; t < 2; ++t) {
    int nt = wave * 2 + t;
    int col = nt * 16 + m;
    float b = bias[col];
    f32x4 a = t ? acc1 : acc0;
#pragma unroll
    for (int r = 0; r < 4; ++r) {
      int rr = nbase + quad * 4 + r;
      if (rr < n) Hout[(size_t)rr * 128 + col] = a[r] + b;
    }
  }
}

// FUSED layer-3 aggregate + segment-sum pool: block computes 16 node rows in
// LDS, reduces per-graph within the block, one atomicAdd per (graph,ch,half).
__global__ __launch_bounds__(256) void agg_pool_kernel(
    const float* __restrict__ H, const int* __restrict__ ptr,
    const int2* __restrict__ emeta, const int* __restrict__ batch,
    float* __restrict__ pool, int n) {
  __shared__ float rows[16][128];
  __shared__ int gids[16];
  int hw = threadIdx.x >> 5, hl = threadIdx.x & 31;
  int nbase = blockIdx.x * 16;
  const f32x4* Hc = (const f32x4*)(H + hl * 4);
#pragma unroll
  for (int rep = 0; rep < 2; ++rep) {
    int nl = hw + rep * 8;
    int node = nbase + nl;
    f32x4 o = (node < n) ? agg_node(Hc, ptr, emeta, node, hl)
                         : (f32x4)0.f;
    *(f32x4*)&rows[nl][hl * 4] = o;
    if (hl == 0) gids[nl] = (node < n) ? batch[node] : -1;
  }
  __syncthreads();
  int half = threadIdx.x >> 7;  // 0: nodes 0-7, 1: nodes 8-15
  int ch = threadIdx.x & 127;
  float acc = 0.f;
  int curg = gids[half * 8];
  for (int i = half * 8; i < half * 8 + 8; ++i) {
    int g = gids[i];
    if (g != curg) {
      if (curg >= 0) atomicAdd(&pool[(size_t)curg * 128 + ch], acc);
      acc = 0.f;
      curg = g;
    }
    if (g >= 0) acc += rows[i][ch];
  }
  if (curg >= 0) atomicAdd(&pool[(size_t)curg * 128 + ch], acc);
}

// MLP head per graph: mean = pool/cnt (cnt from gptr), 2-layer MLP.
__global__ __launch_bounds__(128) void head_kernel(
    const float* __restrict__ pool, const int* __restrict__ gptr,
    const float* __restrict__ Wp1, const float* __restrict__ bp1,
    const float* __restrict__ Wp2, const float* __restrict__ bp2,
    float* __restrict__ out, int G) {
  int g = blockIdx.x;
  int j = threadIdx.x;
  __shared__ float ps[128];
  __shared__ float hs[128];
  int cnt = gptr[g + 1] - gptr[g];
  float inv = 1.0f / (float)max(cnt, 1);
  ps[j] = pool[(size_t)g * 128 + j] * inv;
  __syncthreads();
  float acc = bp1[j];
#pragma unroll 8
  for (int k = 0; k < 128; ++k) acc = fmaf(ps[k], Wp1[k * 128 + j], acc);
  hs[j] = fmaxf(acc, 0.f) * Wp2[j];
  __syncthreads();
  for (int off = 64; off > 0; off >>= 1) {
    if (j < off) hs[j] += hs[j + off];
    __syncthreads();
  }
  if (j == 0) out[g] = hs[0] + bp2[0];
}

extern "C" void kernel_launch(void* const* d_in, const int* in_sizes, int n_in,
                              void* d_out, int out_size, void* d_ws, size_t ws_size,
                              hipStream_t stream) {
  const float* x    = (const float*)d_in[0];
  const int*   eidx = (const int*)d_in[1];
  const int*   batch= (const int*)d_in[2];
  const float* W0 = (const float*)d_in[3];
  const float* b0 = (const float*)d_in[4];
  const float* W1 = (const float*)d_in[5];
  const float* b1 = (const float*)d_in[6];
  const float* W2 = (const float*)d_in[7];
  const float* b2 = (const float*)d_in[8];
  const float* Wp1 = (const float*)d_in[9];
  const float* bp1 = (const float*)d_in[10];
  const float* Wp2 = (const float*)d_in[11];
  const float* bp2 = (const float*)d_in[12];
  float* out = (float*)d_out;

  const int N = in_sizes[0] / 128;
  const int E = in_sizes[1] / 2;
  const int G = out_size;
  const int M = E + N;
  const int T = (N + 1023) / 1024;  // #scan tiles; N<=131072 keeps T<=128

  const int* src = eidx;
  const int* dst = eidx + E;

  char* ws = (char*)d_ws;
  size_t off = 0;
  auto alloc = [&](size_t bytes) -> void* {
    void* p = ws + off;
    off = (off + bytes + 255) & ~(size_t)255;
    return p;
  };
  int*   indeg   = (int*)  alloc((size_t)N * 4);
  int*   cursor  = (int*)  alloc((size_t)N * 4);
  int*   ptr     = (int*)  alloc((size_t)(N + 1) * 4);
  int2*  emeta   = (int2*) alloc((size_t)M * 8);
  float* bufA    = (float*)alloc((size_t)N * 128 * 4);
  float* bufB    = (float*)alloc((size_t)N * 128 * 4);
  int*   gptr    = (int*)  alloc((size_t)(G + 1) * 4);
  float* pool    = (float*)alloc((size_t)G * 128 * 4);
  int*   tilesum = (int*)  alloc((size_t)T * 4);
  short* whi     = (short*)alloc(3 * 16384 * 2);
  short* wlo     = (short*)alloc(3 * 16384 * 2);
  (void)ws_size;

  hipMemsetAsync(indeg, 0, (size_t)N * 4, stream);

  wsplit3_kernel<<<192, 256, 0, stream>>>(W0, W1, W2, whi, wlo);

  const int GB  = (N + 63) / 64;        // gemm1 blocks
  const int CD  = (E + 255) / 256;      // count_deg blocks
  const int GBD = (N + 255) / 256;      // graph_bounds blocks
  const int PZ  = (G * 128 / 4 + 255) / 256;  // pool-zero blocks (float4)
  uberA_kernel<<<GB + CD + GBD + PZ, 256, 0, stream>>>(
      x, whi, wlo, b0, bufA, N, dst, indeg, E, batch, gptr, G, pool,
      GB, CD, GBD, PZ);

  tile_reduce_kernel<<<T, 1024, 0, stream>>>(indeg, tilesum, N);
  scan_emit_kernel<<<T, 1024, 0, stream>>>(indeg, tilesum, ptr, cursor, N, T);
  fill_all_kernel<<<(E + N + 255) / 256, 256, 0, stream>>>(src, dst, indeg, cursor, emeta, E, N);

  dim3 fused_grid((N + 15) / 16);
  agg_gemm_kernel<<<fused_grid, 256, 0, stream>>>(bufA, ptr, emeta,
      whi + 16384, wlo + 16384, b1, bufB, N);
  agg_gemm_kernel<<<fused_grid, 256, 0, stream>>>(bufB, ptr, emeta,
      whi + 2 * 16384, wlo + 2 * 16384, b2, bufA, N);
  agg_pool_kernel<<<fused_grid, 256, 0, stream>>>(bufA, ptr, emeta, batch, pool, N);

  head_kernel<<<G, 128, 0, stream>>>(pool, gptr, Wp1, bp1, Wp2, bp2, out, G);
}